// Round 5
// baseline (1874.954 us; speedup 1.0000x reference)
//
#include <hip/hip_runtime.h>

#define N_NODES 100000
#define M_PAD   100096   // 782 * 128
#define N_EDGES 1600000
#define N_GRAPHS 64
#define HID 256
#define PROJ 128
#define NLAYERS 4

typedef unsigned short u16;
typedef __attribute__((ext_vector_type(8))) short bf16x8;
typedef __attribute__((ext_vector_type(4))) float f32x4;

__device__ __forceinline__ float b2f(u16 u) {
  return __uint_as_float(((unsigned)u) << 16);
}
__device__ __forceinline__ float b2f_lo(unsigned u) {
  return __uint_as_float(u << 16);
}
__device__ __forceinline__ float b2f_hi(unsigned u) {
  return __uint_as_float(u & 0xFFFF0000u);
}
__device__ __forceinline__ u16 f2b(float f) {
  unsigned u = __float_as_uint(f);
  u = (u + 0x7FFF + ((u >> 16) & 1)) >> 16;  // round-to-nearest-even
  return (u16)u;
}
__device__ __forceinline__ void gload16(const void* g, void* l) {
  __builtin_amdgcn_global_load_lds((const __attribute__((address_space(1))) void*)g,
                                   (__attribute__((address_space(3))) void*)l, 16, 0, 0);
}
__device__ __forceinline__ void acc8(float* a, const uint4& v) {
  a[0] += b2f_lo(v.x); a[1] += b2f_hi(v.x);
  a[2] += b2f_lo(v.y); a[3] += b2f_hi(v.y);
  a[4] += b2f_lo(v.z); a[5] += b2f_hi(v.z);
  a[6] += b2f_lo(v.w); a[7] += b2f_hi(v.w);
}

// ---------------------------------------------------------------- CSR -------
__global__ void count_kernel(const int* __restrict__ dst, int* __restrict__ cnt) {
  int e = blockIdx.x * blockDim.x + threadIdx.x;
  if (e < N_EDGES) atomicAdd(&cnt[dst[e]], 1);
}

__global__ void inv_kernel(const int* __restrict__ cnt, float* __restrict__ inv) {
  int n = blockIdx.x * blockDim.x + threadIdx.x;
  if (n < N_NODES) inv[n] = 1.0f / fmaxf((float)cnt[n], 1.0f);
}

// ---- 3-phase multi-block exclusive scan ------------------------------------
#define SCAN_BLK 1024
#define N_SCAN_BLOCKS ((N_NODES + SCAN_BLK - 1) / SCAN_BLK)  // 98

__global__ __launch_bounds__(256) void scan_partial(const int* __restrict__ cnt,
                                                    int* __restrict__ bsum) {
  __shared__ int red[256];
  int t = threadIdx.x;
  int base = blockIdx.x * SCAN_BLK + t * 4;
  int s = 0;
#pragma unroll
  for (int j = 0; j < 4; j++) {
    int i = base + j;
    if (i < N_NODES) s += cnt[i];
  }
  red[t] = s;
  __syncthreads();
  for (int off = 128; off > 0; off >>= 1) {
    if (t < off) red[t] += red[t + off];
    __syncthreads();
  }
  if (t == 0) bsum[blockIdx.x] = red[0];
}

__global__ __launch_bounds__(128) void scan_bsums(const int* __restrict__ bsum,
                                                  int* __restrict__ boff) {
  __shared__ int tile[128];
  int t = threadIdx.x;
  int v = (t < N_SCAN_BLOCKS) ? bsum[t] : 0;
  tile[t] = v;
  __syncthreads();
#pragma unroll
  for (int off = 1; off < 128; off <<= 1) {
    int add = (t >= off) ? tile[t - off] : 0;
    __syncthreads();
    tile[t] += add;
    __syncthreads();
  }
  if (t < N_SCAN_BLOCKS) boff[t] = tile[t] - v;  // exclusive
}

__global__ __launch_bounds__(256) void scan_final(const int* __restrict__ cnt,
                                                  const int* __restrict__ boff,
                                                  int* __restrict__ row_ptr) {
  __shared__ int tsum[256];
  int t = threadIdx.x;
  int base = blockIdx.x * SCAN_BLK + t * 4;
  int v[4];
  int s = 0;
#pragma unroll
  for (int j = 0; j < 4; j++) {
    int i = base + j;
    v[j] = (i < N_NODES) ? cnt[i] : 0;
    s += v[j];
  }
  tsum[t] = s;
  __syncthreads();
#pragma unroll
  for (int off = 1; off < 256; off <<= 1) {
    int add = (t >= off) ? tsum[t - off] : 0;
    __syncthreads();
    tsum[t] += add;
    __syncthreads();
  }
  int excl = tsum[t] - s + boff[blockIdx.x];
#pragma unroll
  for (int j = 0; j < 4; j++) {
    int i = base + j;
    if (i < N_NODES) {
      row_ptr[i] = excl;
      excl += v[j];
    }
  }
  if (blockIdx.x == 0 && t == 0) row_ptr[N_NODES] = N_EDGES;
}

__global__ void fill_kernel(const int* __restrict__ src, const int* __restrict__ dst,
                            const int* __restrict__ row_ptr, int* __restrict__ fill,
                            int* __restrict__ col) {
  int e = blockIdx.x * blockDim.x + threadIdx.x;
  if (e < N_EDGES) {
    int d = dst[e];
    int pos = row_ptr[d] + atomicAdd(&fill[d], 1);
    col[pos] = src[e];
  }
}

// ------------------------------------------------------------ converts ------
__global__ __launch_bounds__(256) void convert_x(const float4* __restrict__ x,
                                                 ushort4* __restrict__ hb) {
  int i = blockIdx.x * blockDim.x + threadIdx.x;  // exactly N_NODES*64 threads
  float4 v = x[i];
  ushort4 o;
  o.x = f2b(v.x); o.y = f2b(v.y); o.z = f2b(v.z); o.w = f2b(v.w);
  hb[i] = o;
}

// Wt[l][n][k] bf16, k<256 -> Wl[l][k][n], k>=256 -> Wr[l][k-256][n]
__global__ __launch_bounds__(256) void convert_w(const float* __restrict__ Wl,
                                                 const float* __restrict__ Wr,
                                                 u16* __restrict__ Wt) {
  int idx = blockIdx.x * blockDim.x + threadIdx.x;  // 4*256*512 threads
  int l = idx >> 17;
  int r = idx & ((1 << 17) - 1);
  int n = r >> 9;
  int k = r & 511;
  float v = (k < 256) ? Wl[(size_t)l * 65536 + k * 256 + n]
                      : Wr[(size_t)l * 65536 + (k - 256) * 256 + n];
  Wt[idx] = f2b(v);
}

// ----------------------------------------------------------- aggregation ----
// one wave per node; two 32-lane halves process alternating edges with 16B loads;
// 4 gathers in flight per half; cross-half merge via shfl_xor(32).
__global__ __launch_bounds__(256) void aggregate_bf16(
    const u16* __restrict__ h, const int* __restrict__ row_ptr,
    const int* __restrict__ col, const float* __restrict__ inv_cnt,
    u16* __restrict__ aggr) {
  int node = blockIdx.x * 4 + (threadIdx.x >> 6);
  int lane = threadIdx.x & 63;
  int half = lane >> 5, l32 = lane & 31;
  int r0 = row_ptr[node], r1 = row_ptr[node + 1];
  float a[8] = {0.f, 0.f, 0.f, 0.f, 0.f, 0.f, 0.f, 0.f};
  int e = r0 + half;
  for (; e + 6 < r1; e += 8) {
    int s0 = col[e], s1 = col[e + 2], s2 = col[e + 4], s3 = col[e + 6];
    uint4 v0 = *((const uint4*)(h + (size_t)s0 * HID) + l32);
    uint4 v1 = *((const uint4*)(h + (size_t)s1 * HID) + l32);
    uint4 v2 = *((const uint4*)(h + (size_t)s2 * HID) + l32);
    uint4 v3 = *((const uint4*)(h + (size_t)s3 * HID) + l32);
    acc8(a, v0); acc8(a, v1); acc8(a, v2); acc8(a, v3);
  }
  for (; e < r1; e += 2) {
    int s0 = col[e];
    uint4 v0 = *((const uint4*)(h + (size_t)s0 * HID) + l32);
    acc8(a, v0);
  }
#pragma unroll
  for (int j = 0; j < 8; j++) a[j] += __shfl_xor(a[j], 32, 64);
  if (half == 0) {
    float inv = inv_cnt[node];
    uint4 o;
    o.x = (unsigned)f2b(a[0] * inv) | ((unsigned)f2b(a[1] * inv) << 16);
    o.y = (unsigned)f2b(a[2] * inv) | ((unsigned)f2b(a[3] * inv) << 16);
    o.z = (unsigned)f2b(a[4] * inv) | ((unsigned)f2b(a[5] * inv) << 16);
    o.w = (unsigned)f2b(a[6] * inv) | ((unsigned)f2b(a[7] * inv) << 16);
    *((uint4*)(aggr + (size_t)node * HID) + l32) = o;
  }
}

// ------------------------------------------------------------ MFMA GEMM -----
// hpre[m][n] = sum_k cat(aggr,h)[m][k] * B[k][n],  B^T given as Wt[n][k].
// 128x128 tile, BK=32, 4 waves each 64x64, 16x16x32 bf16 MFMA.
// 16B-chunk XOR swizzle: LDS chunk-slot c holds global chunk c ^ ((row>>1)&3).
__global__ __launch_bounds__(256) void gemm_mfma(
    const u16* __restrict__ hb, const u16* __restrict__ aggr,
    const u16* __restrict__ Bt, u16* __restrict__ hpre) {
  __shared__ u16 As[128 * 32];
  __shared__ u16 Bs[128 * 32];
  int tid = threadIdx.x;
  int wid = tid >> 6, lane = tid & 63;
  int m0 = blockIdx.x * 128;
  int n0 = blockIdx.y * 128;
  int q = lane >> 4, c = lane & 15;
  int wm = (wid >> 1) * 64, wn = (wid & 1) * 64;

  f32x4 zero = {0.f, 0.f, 0.f, 0.f};
  f32x4 acc[4][4];
#pragma unroll
  for (int mi = 0; mi < 4; mi++)
#pragma unroll
    for (int ni = 0; ni < 4; ni++) acc[mi][ni] = zero;

  // staging geometry (loop-invariant)
  int srow0 = wid * 32 + (lane >> 2);       // t=0 row
  int cg0 = (lane & 3) ^ ((srow0 >> 1) & 3);
  int srow1 = srow0 + 16;                    // t=1 row
  int cg1 = (lane & 3) ^ ((srow1 >> 1) & 3);

  // frag-read LDS offsets (elements), loop-invariant
  int aoff[4], boff[4];
#pragma unroll
  for (int mi = 0; mi < 4; mi++) {
    int row = wm + mi * 16 + c;
    aoff[mi] = row * 32 + ((q ^ ((row >> 1) & 3)) << 3);
  }
#pragma unroll
  for (int ni = 0; ni < 4; ni++) {
    int row = wn + ni * 16 + c;
    boff[ni] = row * 32 + ((q ^ ((row >> 1) & 3)) << 3);
  }

  for (int k0 = 0; k0 < 512; k0 += 32) {
    const u16* Asrc = (k0 < 256) ? aggr : hb;
    int ksrc = k0 & 255;
    gload16(Asrc + ((size_t)(m0 + srow0) * HID + ksrc + cg0 * 8), &As[(wid * 32) * 32]);
    gload16(Asrc + ((size_t)(m0 + srow1) * HID + ksrc + cg1 * 8), &As[(wid * 32 + 16) * 32]);
    gload16(Bt + ((size_t)(n0 + srow0) * 512 + k0 + cg0 * 8), &Bs[(wid * 32) * 32]);
    gload16(Bt + ((size_t)(n0 + srow1) * 512 + k0 + cg1 * 8), &Bs[(wid * 32 + 16) * 32]);
    __syncthreads();
    bf16x8 af[4], bfr[4];
#pragma unroll
    for (int mi = 0; mi < 4; mi++) af[mi] = *(const bf16x8*)&As[aoff[mi]];
#pragma unroll
    for (int ni = 0; ni < 4; ni++) bfr[ni] = *(const bf16x8*)&Bs[boff[ni]];
#pragma unroll
    for (int mi = 0; mi < 4; mi++)
#pragma unroll
      for (int ni = 0; ni < 4; ni++)
        acc[mi][ni] = __builtin_amdgcn_mfma_f32_16x16x32_bf16(af[mi], bfr[ni],
                                                              acc[mi][ni], 0, 0, 0);
    __syncthreads();
  }

  // epilogue: C/D layout col=lane&15, row=(lane>>4)*4+reg
#pragma unroll
  for (int mi = 0; mi < 4; mi++) {
#pragma unroll
    for (int r = 0; r < 4; r++) {
      int gm = m0 + wm + mi * 16 + q * 4 + r;
      if (gm < N_NODES) {
#pragma unroll
        for (int ni = 0; ni < 4; ni++) {
          int gn = n0 + wn + ni * 16 + c;
          hpre[(size_t)gm * HID + gn] = f2b(acc[mi][ni][r]);
        }
      }
    }
  }
}

// ------------------------------------------------------------ batchnorm -----
#define BNR_ROWS 128
__global__ __launch_bounds__(256) void bn_reduce_bf16(const u16* __restrict__ h,
                                                      float* __restrict__ sums) {
  __shared__ float red[256][16];
  int t = threadIdx.x;
  int rs = t >> 5, c = t & 31;
  int r0 = blockIdx.x * BNR_ROWS;
  int r1 = min(r0 + BNR_ROWS, N_NODES);
  float s[8] = {0.f, 0.f, 0.f, 0.f, 0.f, 0.f, 0.f, 0.f};
  float s2[8] = {0.f, 0.f, 0.f, 0.f, 0.f, 0.f, 0.f, 0.f};
  for (int r = r0 + rs; r < r1; r += 8) {
    uint4 v = *((const uint4*)(h + (size_t)r * HID) + c);
    float x0 = b2f_lo(v.x), x1 = b2f_hi(v.x), x2 = b2f_lo(v.y), x3 = b2f_hi(v.y);
    float x4 = b2f_lo(v.z), x5 = b2f_hi(v.z), x6 = b2f_lo(v.w), x7 = b2f_hi(v.w);
    s[0] += x0; s2[0] += x0 * x0; s[1] += x1; s2[1] += x1 * x1;
    s[2] += x2; s2[2] += x2 * x2; s[3] += x3; s2[3] += x3 * x3;
    s[4] += x4; s2[4] += x4 * x4; s[5] += x5; s2[5] += x5 * x5;
    s[6] += x6; s2[6] += x6 * x6; s[7] += x7; s2[7] += x7 * x7;
  }
#pragma unroll
  for (int j = 0; j < 8; j++) {
    red[t][j] = s[j];
    red[t][8 + j] = s2[j];
  }
  __syncthreads();
  if (rs == 0) {  // t == c, 32 threads
#pragma unroll
    for (int k = 1; k < 8; k++) {
#pragma unroll
      for (int j = 0; j < 8; j++) {
        s[j] += red[c + 32 * k][j];
        s2[j] += red[c + 32 * k][8 + j];
      }
    }
#pragma unroll
    for (int j = 0; j < 8; j++) {
      atomicAdd(&sums[c * 8 + j], s[j]);
      atomicAdd(&sums[HID + c * 8 + j], s2[j]);
    }
  }
}

__global__ void bn_finalize(const float* __restrict__ sums,
                            const float* __restrict__ gamma,
                            const float* __restrict__ beta,
                            float* __restrict__ ss) {
  int f = threadIdx.x;
  const float invN = 1.0f / (float)N_NODES;
  float mu = sums[f] * invN;
  float ex2 = sums[HID + f] * invN;
  float var = fmaxf(ex2 - mu * mu, 0.f);
  float sc = gamma[f] * rsqrtf(var + 1e-5f);
  ss[f] = sc;
  ss[HID + f] = beta[f] - mu * sc;
}

__global__ __launch_bounds__(256) void bn_apply_bf16(const uint4* __restrict__ hpre,
                                                     const float* __restrict__ ss,
                                                     uint4* __restrict__ hout) {
  int idx0 = blockIdx.x * blockDim.x + threadIdx.x;
  int cb = (idx0 & 31) * 8;  // column base (row = 32 uint4)
  float sc[8], sh[8];
#pragma unroll
  for (int j = 0; j < 8; j++) { sc[j] = ss[cb + j]; sh[j] = ss[HID + cb + j]; }
  const int total = N_NODES * 32;
  const int step = gridDim.x * blockDim.x;  // 524288, multiple of 32
  for (int i = idx0; i < total; i += step) {
    uint4 v = hpre[i];
    unsigned vv[4] = {v.x, v.y, v.z, v.w};
    unsigned o[4];
#pragma unroll
    for (int j = 0; j < 4; j++) {
      float lo = b2f_lo(vv[j]);
      float hi = b2f_hi(vv[j]);
      lo = fmaxf(fmaf(lo, sc[2 * j], sh[2 * j]), 0.f);
      hi = fmaxf(fmaf(hi, sc[2 * j + 1], sh[2 * j + 1]), 0.f);
      o[j] = (unsigned)f2b(lo) | ((unsigned)f2b(hi) << 16);
    }
    uint4 ov = {o[0], o[1], o[2], o[3]};
    hout[i] = ov;
  }
}

// ----------------------------------------------------------------- pool -----
#define POOL_ROWS 128
__global__ __launch_bounds__(256) void pool_kernel(const u16* __restrict__ h,
                                                   const int* __restrict__ batch,
                                                   float* __restrict__ gacc,
                                                   float* __restrict__ gcnt) {
  int t = threadIdx.x;
  int rs = t >> 5, c = t & 31;
  int r0 = blockIdx.x * POOL_ROWS;
  int r1 = min(r0 + POOL_ROWS, N_NODES);
  float a[8] = {0.f, 0.f, 0.f, 0.f, 0.f, 0.f, 0.f, 0.f};
  float count = 0.f;
  int cur = -1;
  for (int r = r0 + rs; r < r1; r += 8) {
    int b = batch[r];
    if (b != cur) {
      if (cur >= 0) {
#pragma unroll
        for (int j = 0; j < 8; j++)
          atomicAdd(&gacc[(size_t)cur * HID + c * 8 + j], a[j]);
        if (c == 0) atomicAdd(&gcnt[cur], count);
#pragma unroll
        for (int j = 0; j < 8; j++) a[j] = 0.f;
        count = 0.f;
      }
      cur = b;
    }
    uint4 v = *((const uint4*)(h + (size_t)r * HID) + c);
    acc8(a, v);
    count += 1.f;
  }
  if (cur >= 0) {
#pragma unroll
    for (int j = 0; j < 8; j++)
      atomicAdd(&gacc[(size_t)cur * HID + c * 8 + j], a[j]);
    if (c == 0) atomicAdd(&gcnt[cur], count);
  }
}

// ------------------------------------------------------------------ MLP -----
__global__ __launch_bounds__(256) void mlp_kernel(
    const float* __restrict__ gacc, const float* __restrict__ gcnt,
    const float* __restrict__ W1, const float* __restrict__ b1,
    const float* __restrict__ W2, const float* __restrict__ b2,
    float* __restrict__ out) {
  __shared__ float gs[HID];
  __shared__ float ts[HID];
  __shared__ float red[PROJ];
  int g = blockIdx.x;
  int t = threadIdx.x;
  float inv = 1.0f / fmaxf(gcnt[g], 1.0f);
  gs[t] = gacc[(size_t)g * HID + t] * inv;
  __syncthreads();
  float s = b1[t];
  for (int k = 0; k < HID; k++) s = fmaf(gs[k], W1[(size_t)k * HID + t], s);
  ts[t] = fmaxf(s, 0.f);
  __syncthreads();
  float z = 0.f;
  if (t < PROJ) {
    z = b2[t];
    for (int k = 0; k < HID; k++) z = fmaf(ts[k], W2[(size_t)k * PROJ + t], z);
    red[t] = z * z;
  }
  __syncthreads();
  for (int off = PROJ / 2; off > 0; off >>= 1) {
    if (t < off) red[t] += red[t + off];
    __syncthreads();
  }
  float norm = fmaxf(sqrtf(red[0]), 1e-12f);
  if (t < PROJ) out[(size_t)g * PROJ + t] = z / norm;
}

// --------------------------------------------------------------- launch -----
extern "C" void kernel_launch(void* const* d_in, const int* in_sizes, int n_in,
                              void* d_out, int out_size, void* d_ws, size_t ws_size,
                              hipStream_t stream) {
  const float* x = (const float*)d_in[0];
  const int* ei = (const int*)d_in[1];
  const int* src = ei;
  const int* dst = ei + N_EDGES;
  const int* batch = (const int*)d_in[2];
  const float* Wl = (const float*)d_in[3];
  // d_in[4] = bl: per-column bias is exactly cancelled by BatchNorm -> unused
  const float* Wr = (const float*)d_in[5];
  const float* gamma = (const float*)d_in[6];
  const float* beta = (const float*)d_in[7];
  const float* W1 = (const float*)d_in[8];
  const float* b1 = (const float*)d_in[9];
  const float* W2 = (const float*)d_in[10];
  const float* b2 = (const float*)d_in[11];
  float* out = (float*)d_out;

  char* p = (char*)d_ws;
  const size_t HB = (size_t)M_PAD * HID * sizeof(u16);  // 51.25 MB
  u16* hb0 = (u16*)p;    p += HB;
  u16* hb1 = (u16*)p;    p += HB;
  u16* aggr = (u16*)p;   p += HB;
  u16* hpre = (u16*)p;   p += HB;
  u16* Wt = (u16*)p;     p += (size_t)NLAYERS * 512 * HID * sizeof(u16);  // 1 MB
  int* col = (int*)p;    p += (size_t)N_EDGES * sizeof(int);              // 6.4 MB
  int* row_ptr = (int*)p; p += 400016;
  float* inv_cnt = (float*)p; p += (size_t)N_NODES * sizeof(float);
  float* sums = (float*)p;    p += 512 * sizeof(float);
  float* ss = (float*)p;      p += 512 * sizeof(float);
  float* gacc = (float*)p;    p += (size_t)N_GRAPHS * HID * sizeof(float);
  float* gcnt = (float*)p;    p += N_GRAPHS * sizeof(float);
  int* bsum = (int*)p;        p += 128 * sizeof(int);
  int* boff = (int*)p;        p += 128 * sizeof(int);

  // transient CSR-build arrays overlaid into hpre (first written in layer-0 gemm)
  int* counts = (int*)hpre;
  int* fill = counts + N_NODES;

  // ---- build CSR (once; edge_index is layer-invariant) ----
  hipMemsetAsync(counts, 0, 2 * (size_t)N_NODES * sizeof(int), stream);
  count_kernel<<<(N_EDGES + 255) / 256, 256, 0, stream>>>(dst, counts);
  inv_kernel<<<(N_NODES + 255) / 256, 256, 0, stream>>>(counts, inv_cnt);
  scan_partial<<<N_SCAN_BLOCKS, 256, 0, stream>>>(counts, bsum);
  scan_bsums<<<1, 128, 0, stream>>>(bsum, boff);
  scan_final<<<N_SCAN_BLOCKS, 256, 0, stream>>>(counts, boff, row_ptr);
  fill_kernel<<<(N_EDGES + 255) / 256, 256, 0, stream>>>(src, dst, row_ptr, fill, col);

  // ---- one-time converts ----
  convert_x<<<N_NODES / 4, 256, 0, stream>>>((const float4*)x, (ushort4*)hb0);
  convert_w<<<(NLAYERS * 512 * HID) / 256, 256, 0, stream>>>(Wl, Wr, Wt);

  u16* hcur = hb0;
  u16* hnext = hb1;
  for (int l = 0; l < NLAYERS; l++) {
    aggregate_bf16<<<N_NODES / 4, 256, 0, stream>>>(hcur, row_ptr, col, inv_cnt, aggr);
    gemm_mfma<<<dim3(M_PAD / 128, HID / 128), 256, 0, stream>>>(
        hcur, aggr, Wt + (size_t)l * 512 * HID, hpre);
    hipMemsetAsync(sums, 0, 512 * sizeof(float), stream);
    bn_reduce_bf16<<<(N_NODES + BNR_ROWS - 1) / BNR_ROWS, 256, 0, stream>>>(hpre, sums);
    bn_finalize<<<1, 256, 0, stream>>>(sums, gamma + (size_t)l * HID,
                                       beta + (size_t)l * HID, ss);
    bn_apply_bf16<<<2048, 256, 0, stream>>>((const uint4*)hpre, ss, (uint4*)hnext);
    u16* t = hcur; hcur = hnext; hnext = t;
  }

  hipMemsetAsync(gacc, 0, (size_t)(N_GRAPHS * HID + N_GRAPHS) * sizeof(float), stream);
  pool_kernel<<<(N_NODES + POOL_ROWS - 1) / POOL_ROWS, 256, 0, stream>>>(
      hcur, batch, gacc, gcnt);
  mlp_kernel<<<N_GRAPHS, 256, 0, stream>>>(gacc, gcnt, W1, b1, W2, b2, out);
}

// Round 6
// 1226.612 us; speedup vs baseline: 1.5286x; 1.5286x over previous
//
#include <hip/hip_runtime.h>

#define N_NODES 100000
#define M_PAD   100096   // 782 * 128
#define N_EDGES 1600000
#define N_GRAPHS 64
#define HID 256
#define PROJ 128
#define NLAYERS 4

typedef unsigned short u16;
typedef __attribute__((ext_vector_type(8))) short bf16x8;
typedef __attribute__((ext_vector_type(4))) float f32x4;

__device__ __forceinline__ float b2f(u16 u) {
  return __uint_as_float(((unsigned)u) << 16);
}
__device__ __forceinline__ float b2f_lo(unsigned u) {
  return __uint_as_float(u << 16);
}
__device__ __forceinline__ float b2f_hi(unsigned u) {
  return __uint_as_float(u & 0xFFFF0000u);
}
__device__ __forceinline__ u16 f2b(float f) {
  unsigned u = __float_as_uint(f);
  u = (u + 0x7FFF + ((u >> 16) & 1)) >> 16;  // round-to-nearest-even
  return (u16)u;
}
__device__ __forceinline__ void gload16(const void* g, void* l) {
  __builtin_amdgcn_global_load_lds((const __attribute__((address_space(1))) void*)g,
                                   (__attribute__((address_space(3))) void*)l, 16, 0, 0);
}
__device__ __forceinline__ void acc8(float* a, const uint4& v) {
  a[0] += b2f_lo(v.x); a[1] += b2f_hi(v.x);
  a[2] += b2f_lo(v.y); a[3] += b2f_hi(v.y);
  a[4] += b2f_lo(v.z); a[5] += b2f_hi(v.z);
  a[6] += b2f_lo(v.w); a[7] += b2f_hi(v.w);
}

// ---------------------------------------------------------------- CSR -------
__global__ void count_kernel(const int* __restrict__ dst, int* __restrict__ cnt) {
  int e = blockIdx.x * blockDim.x + threadIdx.x;
  if (e < N_EDGES) atomicAdd(&cnt[dst[e]], 1);
}

__global__ void inv_kernel(const int* __restrict__ cnt, float* __restrict__ inv) {
  int n = blockIdx.x * blockDim.x + threadIdx.x;
  if (n < N_NODES) inv[n] = 1.0f / fmaxf((float)cnt[n], 1.0f);
}

// ---- 3-phase multi-block exclusive scan ------------------------------------
#define SCAN_BLK 1024
#define N_SCAN_BLOCKS ((N_NODES + SCAN_BLK - 1) / SCAN_BLK)  // 98

__global__ __launch_bounds__(256) void scan_partial(const int* __restrict__ cnt,
                                                    int* __restrict__ bsum) {
  __shared__ int red[256];
  int t = threadIdx.x;
  int base = blockIdx.x * SCAN_BLK + t * 4;
  int s = 0;
#pragma unroll
  for (int j = 0; j < 4; j++) {
    int i = base + j;
    if (i < N_NODES) s += cnt[i];
  }
  red[t] = s;
  __syncthreads();
  for (int off = 128; off > 0; off >>= 1) {
    if (t < off) red[t] += red[t + off];
    __syncthreads();
  }
  if (t == 0) bsum[blockIdx.x] = red[0];
}

__global__ __launch_bounds__(128) void scan_bsums(const int* __restrict__ bsum,
                                                  int* __restrict__ boff) {
  __shared__ int tile[128];
  int t = threadIdx.x;
  int v = (t < N_SCAN_BLOCKS) ? bsum[t] : 0;
  tile[t] = v;
  __syncthreads();
#pragma unroll
  for (int off = 1; off < 128; off <<= 1) {
    int add = (t >= off) ? tile[t - off] : 0;
    __syncthreads();
    tile[t] += add;
    __syncthreads();
  }
  if (t < N_SCAN_BLOCKS) boff[t] = tile[t] - v;  // exclusive
}

__global__ __launch_bounds__(256) void scan_final(const int* __restrict__ cnt,
                                                  const int* __restrict__ boff,
                                                  int* __restrict__ row_ptr) {
  __shared__ int tsum[256];
  int t = threadIdx.x;
  int base = blockIdx.x * SCAN_BLK + t * 4;
  int v[4];
  int s = 0;
#pragma unroll
  for (int j = 0; j < 4; j++) {
    int i = base + j;
    v[j] = (i < N_NODES) ? cnt[i] : 0;
    s += v[j];
  }
  tsum[t] = s;
  __syncthreads();
#pragma unroll
  for (int off = 1; off < 256; off <<= 1) {
    int add = (t >= off) ? tsum[t - off] : 0;
    __syncthreads();
    tsum[t] += add;
    __syncthreads();
  }
  int excl = tsum[t] - s + boff[blockIdx.x];
#pragma unroll
  for (int j = 0; j < 4; j++) {
    int i = base + j;
    if (i < N_NODES) {
      row_ptr[i] = excl;
      excl += v[j];
    }
  }
  if (blockIdx.x == 0 && t == 0) row_ptr[N_NODES] = N_EDGES;
}

__global__ void fill_kernel(const int* __restrict__ src, const int* __restrict__ dst,
                            const int* __restrict__ row_ptr, int* __restrict__ fill,
                            int* __restrict__ col) {
  int e = blockIdx.x * blockDim.x + threadIdx.x;
  if (e < N_EDGES) {
    int d = dst[e];
    int pos = row_ptr[d] + atomicAdd(&fill[d], 1);
    col[pos] = src[e];
  }
}

// ------------------------------------------------------------ converts ------
__global__ __launch_bounds__(256) void convert_x(const float4* __restrict__ x,
                                                 ushort4* __restrict__ hb) {
  int i = blockIdx.x * blockDim.x + threadIdx.x;  // exactly N_NODES*64 threads
  float4 v = x[i];
  ushort4 o;
  o.x = f2b(v.x); o.y = f2b(v.y); o.z = f2b(v.z); o.w = f2b(v.w);
  hb[i] = o;
}

// Wt[l][n][k] bf16, k<256 -> Wl[l][k][n], k>=256 -> Wr[l][k-256][n]
__global__ __launch_bounds__(256) void convert_w(const float* __restrict__ Wl,
                                                 const float* __restrict__ Wr,
                                                 u16* __restrict__ Wt) {
  int idx = blockIdx.x * blockDim.x + threadIdx.x;  // 4*256*512 threads
  int l = idx >> 17;
  int r = idx & ((1 << 17) - 1);
  int n = r >> 9;
  int k = r & 511;
  float v = (k < 256) ? Wl[(size_t)l * 65536 + k * 256 + n]
                      : Wr[(size_t)l * 65536 + (k - 256) * 256 + n];
  Wt[idx] = f2b(v);
}

// ----------------------------------------------------------- aggregation ----
// one wave per node; two 32-lane halves process alternating edges with 16B loads;
// 4 gathers in flight per half; cross-half merge via shfl_xor(32).
__global__ __launch_bounds__(256) void aggregate_bf16(
    const u16* __restrict__ h, const int* __restrict__ row_ptr,
    const int* __restrict__ col, const float* __restrict__ inv_cnt,
    u16* __restrict__ aggr) {
  int node = blockIdx.x * 4 + (threadIdx.x >> 6);
  int lane = threadIdx.x & 63;
  int half = lane >> 5, l32 = lane & 31;
  int r0 = row_ptr[node], r1 = row_ptr[node + 1];
  float a[8] = {0.f, 0.f, 0.f, 0.f, 0.f, 0.f, 0.f, 0.f};
  int e = r0 + half;
  for (; e + 6 < r1; e += 8) {
    int s0 = col[e], s1 = col[e + 2], s2 = col[e + 4], s3 = col[e + 6];
    uint4 v0 = *((const uint4*)(h + (size_t)s0 * HID) + l32);
    uint4 v1 = *((const uint4*)(h + (size_t)s1 * HID) + l32);
    uint4 v2 = *((const uint4*)(h + (size_t)s2 * HID) + l32);
    uint4 v3 = *((const uint4*)(h + (size_t)s3 * HID) + l32);
    acc8(a, v0); acc8(a, v1); acc8(a, v2); acc8(a, v3);
  }
  for (; e < r1; e += 2) {
    int s0 = col[e];
    uint4 v0 = *((const uint4*)(h + (size_t)s0 * HID) + l32);
    acc8(a, v0);
  }
#pragma unroll
  for (int j = 0; j < 8; j++) a[j] += __shfl_xor(a[j], 32, 64);
  if (half == 0) {
    float inv = inv_cnt[node];
    uint4 o;
    o.x = (unsigned)f2b(a[0] * inv) | ((unsigned)f2b(a[1] * inv) << 16);
    o.y = (unsigned)f2b(a[2] * inv) | ((unsigned)f2b(a[3] * inv) << 16);
    o.z = (unsigned)f2b(a[4] * inv) | ((unsigned)f2b(a[5] * inv) << 16);
    o.w = (unsigned)f2b(a[6] * inv) | ((unsigned)f2b(a[7] * inv) << 16);
    *((uint4*)(aggr + (size_t)node * HID) + l32) = o;
  }
}

// ------------------------------------------------------------ MFMA GEMM -----
// hpre[m][n] = sum_k cat(aggr,h)[m][k] * B[k][n],  B^T given as Wt[n][k].
// 128x128 tile, BK=32, 4 waves each 64x64, 16x16x32 bf16 MFMA.
// 16B-chunk XOR swizzle: LDS chunk-slot c holds global chunk c ^ ((row>>1)&3).
__global__ __launch_bounds__(256) void gemm_mfma(
    const u16* __restrict__ hb, const u16* __restrict__ aggr,
    const u16* __restrict__ Bt, u16* __restrict__ hpre) {
  __shared__ u16 As[128 * 32];
  __shared__ u16 Bs[128 * 32];
  int tid = threadIdx.x;
  int wid = tid >> 6, lane = tid & 63;
  int m0 = blockIdx.x * 128;
  int n0 = blockIdx.y * 128;
  int q = lane >> 4, c = lane & 15;
  int wm = (wid >> 1) * 64, wn = (wid & 1) * 64;

  f32x4 zero = {0.f, 0.f, 0.f, 0.f};
  f32x4 acc[4][4];
#pragma unroll
  for (int mi = 0; mi < 4; mi++)
#pragma unroll
    for (int ni = 0; ni < 4; ni++) acc[mi][ni] = zero;

  // staging geometry (loop-invariant)
  int srow0 = wid * 32 + (lane >> 2);       // t=0 row
  int cg0 = (lane & 3) ^ ((srow0 >> 1) & 3);
  int srow1 = srow0 + 16;                    // t=1 row
  int cg1 = (lane & 3) ^ ((srow1 >> 1) & 3);

  // frag-read LDS offsets (elements), loop-invariant
  int aoff[4], boff[4];
#pragma unroll
  for (int mi = 0; mi < 4; mi++) {
    int row = wm + mi * 16 + c;
    aoff[mi] = row * 32 + ((q ^ ((row >> 1) & 3)) << 3);
  }
#pragma unroll
  for (int ni = 0; ni < 4; ni++) {
    int row = wn + ni * 16 + c;
    boff[ni] = row * 32 + ((q ^ ((row >> 1) & 3)) << 3);
  }

  for (int k0 = 0; k0 < 512; k0 += 32) {
    const u16* Asrc = (k0 < 256) ? aggr : hb;
    int ksrc = k0 & 255;
    gload16(Asrc + ((size_t)(m0 + srow0) * HID + ksrc + cg0 * 8), &As[(wid * 32) * 32]);
    gload16(Asrc + ((size_t)(m0 + srow1) * HID + ksrc + cg1 * 8), &As[(wid * 32 + 16) * 32]);
    gload16(Bt + ((size_t)(n0 + srow0) * 512 + k0 + cg0 * 8), &Bs[(wid * 32) * 32]);
    gload16(Bt + ((size_t)(n0 + srow1) * 512 + k0 + cg1 * 8), &Bs[(wid * 32 + 16) * 32]);
    __syncthreads();
    bf16x8 af[4], bfr[4];
#pragma unroll
    for (int mi = 0; mi < 4; mi++) af[mi] = *(const bf16x8*)&As[aoff[mi]];
#pragma unroll
    for (int ni = 0; ni < 4; ni++) bfr[ni] = *(const bf16x8*)&Bs[boff[ni]];
#pragma unroll
    for (int mi = 0; mi < 4; mi++)
#pragma unroll
      for (int ni = 0; ni < 4; ni++)
        acc[mi][ni] = __builtin_amdgcn_mfma_f32_16x16x32_bf16(af[mi], bfr[ni],
                                                              acc[mi][ni], 0, 0, 0);
    __syncthreads();
  }

  // epilogue: C/D layout col=lane&15, row=(lane>>4)*4+reg
#pragma unroll
  for (int mi = 0; mi < 4; mi++) {
#pragma unroll
    for (int r = 0; r < 4; r++) {
      int gm = m0 + wm + mi * 16 + q * 4 + r;
      if (gm < N_NODES) {
#pragma unroll
        for (int ni = 0; ni < 4; ni++) {
          int gn = n0 + wn + ni * 16 + c;
          hpre[(size_t)gm * HID + gn] = f2b(acc[mi][ni][r]);
        }
      }
    }
  }
}

// --------------------------------- batchnorm (two-stage, atomic-free) -------
#define BNS_BLOCKS 200
#define BNS_ROWS 500  // 200*500 == N_NODES
__global__ __launch_bounds__(256) void bn_partial(const u16* __restrict__ h,
                                                  float* __restrict__ psum) {
  __shared__ float red[256][17];
  int t = threadIdx.x;
  int rs = t >> 5, c = t & 31;
  int r0 = blockIdx.x * BNS_ROWS;
  int r1 = r0 + BNS_ROWS;
  float s[8] = {0.f, 0.f, 0.f, 0.f, 0.f, 0.f, 0.f, 0.f};
  float s2[8] = {0.f, 0.f, 0.f, 0.f, 0.f, 0.f, 0.f, 0.f};
  for (int r = r0 + rs; r < r1; r += 8) {
    uint4 v = *((const uint4*)(h + (size_t)r * HID) + c);
    float x0 = b2f_lo(v.x), x1 = b2f_hi(v.x), x2 = b2f_lo(v.y), x3 = b2f_hi(v.y);
    float x4 = b2f_lo(v.z), x5 = b2f_hi(v.z), x6 = b2f_lo(v.w), x7 = b2f_hi(v.w);
    s[0] += x0; s2[0] += x0 * x0; s[1] += x1; s2[1] += x1 * x1;
    s[2] += x2; s2[2] += x2 * x2; s[3] += x3; s2[3] += x3 * x3;
    s[4] += x4; s2[4] += x4 * x4; s[5] += x5; s2[5] += x5 * x5;
    s[6] += x6; s2[6] += x6 * x6; s[7] += x7; s2[7] += x7 * x7;
  }
#pragma unroll
  for (int j = 0; j < 8; j++) {
    red[t][j] = s[j];
    red[t][8 + j] = s2[j];
  }
  __syncthreads();
  // thread t reduces column f=t across the 8 row-strips
  int cc = t >> 3, j = t & 7;
  float sum = 0.f, sq = 0.f;
#pragma unroll
  for (int k = 0; k < 8; k++) {
    sum += red[k * 32 + cc][j];
    sq += red[k * 32 + cc][8 + j];
  }
  psum[(size_t)blockIdx.x * 512 + t] = sum;
  psum[(size_t)blockIdx.x * 512 + 256 + t] = sq;
}

__global__ __launch_bounds__(256) void bn_finalize2(const float* __restrict__ psum,
                                                    const float* __restrict__ gamma,
                                                    const float* __restrict__ beta,
                                                    float* __restrict__ ss) {
  int f = threadIdx.x;
  float sum = 0.f, sq = 0.f;
  for (int b = 0; b < BNS_BLOCKS; b++) {
    sum += psum[(size_t)b * 512 + f];
    sq += psum[(size_t)b * 512 + 256 + f];
  }
  const float invN = 1.0f / (float)N_NODES;
  float mu = sum * invN;
  float ex2 = sq * invN;
  float var = fmaxf(ex2 - mu * mu, 0.f);
  float sc = gamma[f] * rsqrtf(var + 1e-5f);
  ss[f] = sc;
  ss[HID + f] = beta[f] - mu * sc;
}

__global__ __launch_bounds__(256) void bn_apply_bf16(const uint4* __restrict__ hpre,
                                                     const float* __restrict__ ss,
                                                     uint4* __restrict__ hout) {
  int idx0 = blockIdx.x * blockDim.x + threadIdx.x;
  int cb = (idx0 & 31) * 8;  // column base (row = 32 uint4)
  float sc[8], sh[8];
#pragma unroll
  for (int j = 0; j < 8; j++) { sc[j] = ss[cb + j]; sh[j] = ss[HID + cb + j]; }
  const int total = N_NODES * 32;
  const int step = gridDim.x * blockDim.x;  // 524288, multiple of 32
  for (int i = idx0; i < total; i += step) {
    uint4 v = hpre[i];
    unsigned vv[4] = {v.x, v.y, v.z, v.w};
    unsigned o[4];
#pragma unroll
    for (int j = 0; j < 4; j++) {
      float lo = b2f_lo(vv[j]);
      float hi = b2f_hi(vv[j]);
      lo = fmaxf(fmaf(lo, sc[2 * j], sh[2 * j]), 0.f);
      hi = fmaxf(fmaf(hi, sc[2 * j + 1], sh[2 * j + 1]), 0.f);
      o[j] = (unsigned)f2b(lo) | ((unsigned)f2b(hi) << 16);
    }
    uint4 ov = {o[0], o[1], o[2], o[3]};
    hout[i] = ov;
  }
}

// ----------------------------- pool + MLP (fused, one block/graph) ----------
__global__ __launch_bounds__(256) void pool_mlp(
    const u16* __restrict__ h, const int* __restrict__ batch,
    const float* __restrict__ W1, const float* __restrict__ b1,
    const float* __restrict__ W2, const float* __restrict__ b2,
    float* __restrict__ out) {
  __shared__ float red[256][9];
  __shared__ float gs[HID];
  __shared__ float ts[HID];
  __shared__ float rn[PROJ];
  int g = blockIdx.x;
  int t = threadIdx.x;
  // row range of graph g in sorted batch: [lo, hi)
  int a = 0, b = N_NODES;
  while (a < b) { int m = (a + b) >> 1; if (batch[m] < g) a = m + 1; else b = m; }
  int lo = a;
  b = N_NODES;
  while (a < b) { int m = (a + b) >> 1; if (batch[m] < g + 1) a = m + 1; else b = m; }
  int hi = a;

  int rs = t >> 5, c = t & 31;
  float acc[8] = {0.f, 0.f, 0.f, 0.f, 0.f, 0.f, 0.f, 0.f};
  for (int r = lo + rs; r < hi; r += 8) {
    uint4 v = *((const uint4*)(h + (size_t)r * HID) + c);
    acc8(acc, v);
  }
#pragma unroll
  for (int j = 0; j < 8; j++) red[t][j] = acc[j];
  __syncthreads();
  int cc = t >> 3, j = t & 7;
  float sum = 0.f;
#pragma unroll
  for (int k = 0; k < 8; k++) sum += red[k * 32 + cc][j];
  float inv = 1.0f / fmaxf((float)(hi - lo), 1.0f);
  gs[t] = sum * inv;
  __syncthreads();

  float s = b1[t];
  for (int k = 0; k < HID; k++) s = fmaf(gs[k], W1[(size_t)k * HID + t], s);
  ts[t] = fmaxf(s, 0.f);
  __syncthreads();
  float z = 0.f;
  if (t < PROJ) {
    z = b2[t];
    for (int k = 0; k < HID; k++) z = fmaf(ts[k], W2[(size_t)k * PROJ + t], z);
    rn[t] = z * z;
  }
  __syncthreads();
  for (int off = PROJ / 2; off > 0; off >>= 1) {
    if (t < off) rn[t] += rn[t + off];
    __syncthreads();
  }
  float norm = fmaxf(sqrtf(rn[0]), 1e-12f);
  if (t < PROJ) out[(size_t)g * PROJ + t] = z / norm;
}

// --------------------------------------------------------------- launch -----
extern "C" void kernel_launch(void* const* d_in, const int* in_sizes, int n_in,
                              void* d_out, int out_size, void* d_ws, size_t ws_size,
                              hipStream_t stream) {
  const float* x = (const float*)d_in[0];
  const int* ei = (const int*)d_in[1];
  const int* src = ei;
  const int* dst = ei + N_EDGES;
  const int* batch = (const int*)d_in[2];
  const float* Wl = (const float*)d_in[3];
  // d_in[4] = bl: per-column bias is exactly cancelled by BatchNorm -> unused
  const float* Wr = (const float*)d_in[5];
  const float* gamma = (const float*)d_in[6];
  const float* beta = (const float*)d_in[7];
  const float* W1 = (const float*)d_in[8];
  const float* b1 = (const float*)d_in[9];
  const float* W2 = (const float*)d_in[10];
  const float* b2 = (const float*)d_in[11];
  float* out = (float*)d_out;

  char* p = (char*)d_ws;
  const size_t HB = (size_t)M_PAD * HID * sizeof(u16);  // 51.25 MB
  u16* hb0 = (u16*)p;    p += HB;
  u16* hb1 = (u16*)p;    p += HB;
  u16* aggr = (u16*)p;   p += HB;
  u16* hpre = (u16*)p;   p += HB;
  u16* Wt = (u16*)p;     p += (size_t)NLAYERS * 512 * HID * sizeof(u16);  // 1 MB
  int* col = (int*)p;    p += (size_t)N_EDGES * sizeof(int);              // 6.4 MB
  int* row_ptr = (int*)p; p += 400016;
  float* inv_cnt = (float*)p; p += (size_t)N_NODES * sizeof(float);
  float* psum = (float*)p;    p += (size_t)BNS_BLOCKS * 512 * sizeof(float);
  float* ss = (float*)p;      p += 512 * sizeof(float);
  int* bsum = (int*)p;        p += 128 * sizeof(int);
  int* boff = (int*)p;        p += 128 * sizeof(int);

  // transient CSR-build arrays overlaid into hpre (first written in layer-0 gemm)
  int* counts = (int*)hpre;
  int* fill = counts + N_NODES;

  // ---- build CSR (once; edge_index is layer-invariant) ----
  hipMemsetAsync(counts, 0, 2 * (size_t)N_NODES * sizeof(int), stream);
  count_kernel<<<(N_EDGES + 255) / 256, 256, 0, stream>>>(dst, counts);
  inv_kernel<<<(N_NODES + 255) / 256, 256, 0, stream>>>(counts, inv_cnt);
  scan_partial<<<N_SCAN_BLOCKS, 256, 0, stream>>>(counts, bsum);
  scan_bsums<<<1, 128, 0, stream>>>(bsum, boff);
  scan_final<<<N_SCAN_BLOCKS, 256, 0, stream>>>(counts, boff, row_ptr);
  fill_kernel<<<(N_EDGES + 255) / 256, 256, 0, stream>>>(src, dst, row_ptr, fill, col);

  // ---- one-time converts ----
  convert_x<<<N_NODES / 4, 256, 0, stream>>>((const float4*)x, (ushort4*)hb0);
  convert_w<<<(NLAYERS * 512 * HID) / 256, 256, 0, stream>>>(Wl, Wr, Wt);

  u16* hcur = hb0;
  u16* hnext = hb1;
  for (int l = 0; l < NLAYERS; l++) {
    aggregate_bf16<<<N_NODES / 4, 256, 0, stream>>>(hcur, row_ptr, col, inv_cnt, aggr);
    gemm_mfma<<<dim3(M_PAD / 128, HID / 128), 256, 0, stream>>>(
        hcur, aggr, Wt + (size_t)l * 512 * HID, hpre);
    bn_partial<<<BNS_BLOCKS, 256, 0, stream>>>(hpre, psum);
    bn_finalize2<<<1, 256, 0, stream>>>(psum, gamma + (size_t)l * HID,
                                        beta + (size_t)l * HID, ss);
    bn_apply_bf16<<<2048, 256, 0, stream>>>((const uint4*)hpre, ss, (uint4*)hnext);
    u16* t = hcur; hcur = hnext; hnext = t;
  }

  pool_mlp<<<N_GRAPHS, 256, 0, stream>>>(hcur, batch, W1, b1, W2, b2, out);
}

// Round 7
// 1188.127 us; speedup vs baseline: 1.5781x; 1.0324x over previous
//
#include <hip/hip_runtime.h>

#define N_NODES 100000
#define M_PAD   100096   // 782 * 128
#define N_MBLK  782
#define N_EDGES 1600000
#define N_GRAPHS 64
#define HID 256
#define PROJ 128
#define NLAYERS 4

typedef unsigned short u16;
typedef __attribute__((ext_vector_type(8))) short bf16x8;
typedef __attribute__((ext_vector_type(4))) float f32x4;

__device__ __forceinline__ float b2f(u16 u) {
  return __uint_as_float(((unsigned)u) << 16);
}
__device__ __forceinline__ float b2f_lo(unsigned u) {
  return __uint_as_float(u << 16);
}
__device__ __forceinline__ float b2f_hi(unsigned u) {
  return __uint_as_float(u & 0xFFFF0000u);
}
__device__ __forceinline__ u16 f2b(float f) {
  unsigned u = __float_as_uint(f);
  u = (u + 0x7FFF + ((u >> 16) & 1)) >> 16;  // round-to-nearest-even
  return (u16)u;
}
__device__ __forceinline__ void gload16(const void* g, void* l) {
  __builtin_amdgcn_global_load_lds((const __attribute__((address_space(1))) void*)g,
                                   (__attribute__((address_space(3))) void*)l, 16, 0, 0);
}
__device__ __forceinline__ void acc8(float* a, const uint4& v) {
  a[0] += b2f_lo(v.x); a[1] += b2f_hi(v.x);
  a[2] += b2f_lo(v.y); a[3] += b2f_hi(v.y);
  a[4] += b2f_lo(v.z); a[5] += b2f_hi(v.z);
  a[6] += b2f_lo(v.w); a[7] += b2f_hi(v.w);
}

// ---------------------------------------------------------------- CSR -------
__global__ void count_kernel(const int* __restrict__ dst, int* __restrict__ cnt) {
  int e = blockIdx.x * blockDim.x + threadIdx.x;
  if (e < N_EDGES) atomicAdd(&cnt[dst[e]], 1);
}

__global__ void inv_kernel(const int* __restrict__ cnt, float* __restrict__ inv) {
  int n = blockIdx.x * blockDim.x + threadIdx.x;
  if (n < N_NODES) inv[n] = 1.0f / fmaxf((float)cnt[n], 1.0f);
}

#define SCAN_BLK 1024
#define N_SCAN_BLOCKS ((N_NODES + SCAN_BLK - 1) / SCAN_BLK)  // 98

__global__ __launch_bounds__(256) void scan_partial(const int* __restrict__ cnt,
                                                    int* __restrict__ bsum) {
  __shared__ int red[256];
  int t = threadIdx.x;
  int base = blockIdx.x * SCAN_BLK + t * 4;
  int s = 0;
#pragma unroll
  for (int j = 0; j < 4; j++) {
    int i = base + j;
    if (i < N_NODES) s += cnt[i];
  }
  red[t] = s;
  __syncthreads();
  for (int off = 128; off > 0; off >>= 1) {
    if (t < off) red[t] += red[t + off];
    __syncthreads();
  }
  if (t == 0) bsum[blockIdx.x] = red[0];
}

__global__ __launch_bounds__(128) void scan_bsums(const int* __restrict__ bsum,
                                                  int* __restrict__ boff) {
  __shared__ int tile[128];
  int t = threadIdx.x;
  int v = (t < N_SCAN_BLOCKS) ? bsum[t] : 0;
  tile[t] = v;
  __syncthreads();
#pragma unroll
  for (int off = 1; off < 128; off <<= 1) {
    int add = (t >= off) ? tile[t - off] : 0;
    __syncthreads();
    tile[t] += add;
    __syncthreads();
  }
  if (t < N_SCAN_BLOCKS) boff[t] = tile[t] - v;  // exclusive
}

__global__ __launch_bounds__(256) void scan_final(const int* __restrict__ cnt,
                                                  const int* __restrict__ boff,
                                                  int* __restrict__ row_ptr) {
  __shared__ int tsum[256];
  int t = threadIdx.x;
  int base = blockIdx.x * SCAN_BLK + t * 4;
  int v[4];
  int s = 0;
#pragma unroll
  for (int j = 0; j < 4; j++) {
    int i = base + j;
    v[j] = (i < N_NODES) ? cnt[i] : 0;
    s += v[j];
  }
  tsum[t] = s;
  __syncthreads();
#pragma unroll
  for (int off = 1; off < 256; off <<= 1) {
    int add = (t >= off) ? tsum[t - off] : 0;
    __syncthreads();
    tsum[t] += add;
    __syncthreads();
  }
  int excl = tsum[t] - s + boff[blockIdx.x];
#pragma unroll
  for (int j = 0; j < 4; j++) {
    int i = base + j;
    if (i < N_NODES) {
      row_ptr[i] = excl;
      excl += v[j];
    }
  }
  if (blockIdx.x == 0 && t == 0) row_ptr[N_NODES] = N_EDGES;
}

__global__ void fill_kernel(const int* __restrict__ src, const int* __restrict__ dst,
                            const int* __restrict__ row_ptr, int* __restrict__ fill,
                            int* __restrict__ col) {
  int e = blockIdx.x * blockDim.x + threadIdx.x;
  if (e < N_EDGES) {
    int d = dst[e];
    int pos = row_ptr[d] + atomicAdd(&fill[d], 1);
    col[pos] = src[e];
  }
}

// ------------------------------------------------------------ converts ------
__global__ __launch_bounds__(256) void convert_x(const float4* __restrict__ x,
                                                 ushort4* __restrict__ hb) {
  int i = blockIdx.x * blockDim.x + threadIdx.x;  // exactly N_NODES*64 threads
  float4 v = x[i];
  ushort4 o;
  o.x = f2b(v.x); o.y = f2b(v.y); o.z = f2b(v.z); o.w = f2b(v.w);
  hb[i] = o;
}

// Wt[l][n][k] bf16, k<256 -> Wl[l][k][n], k>=256 -> Wr[l][k-256][n]
__global__ __launch_bounds__(256) void convert_w(const float* __restrict__ Wl,
                                                 const float* __restrict__ Wr,
                                                 u16* __restrict__ Wt) {
  int idx = blockIdx.x * blockDim.x + threadIdx.x;  // 4*256*512 threads
  int l = idx >> 17;
  int r = idx & ((1 << 17) - 1);
  int n = r >> 9;
  int k = r & 511;
  float v = (k < 256) ? Wl[(size_t)l * 65536 + k * 256 + n]
                      : Wr[(size_t)l * 65536 + (k - 256) * 256 + n];
  Wt[idx] = f2b(v);
}

// ----------------------------------------------------------- aggregation ----
// one wave per node; two 32-lane halves walk alternating edges with 16B loads;
// up to 8 gathers in flight per half; cross-half merge via shfl_xor(32).
__global__ __launch_bounds__(256) void aggregate_bf16(
    const u16* __restrict__ h, const int* __restrict__ row_ptr,
    const int* __restrict__ col, const float* __restrict__ inv_cnt,
    u16* __restrict__ aggr) {
  int node = blockIdx.x * 4 + (threadIdx.x >> 6);
  int lane = threadIdx.x & 63;
  int half = lane >> 5, l32 = lane & 31;
  int r0 = row_ptr[node], r1 = row_ptr[node + 1];
  float a[8] = {0.f, 0.f, 0.f, 0.f, 0.f, 0.f, 0.f, 0.f};
  int e = r0 + half;
  for (; e + 14 < r1; e += 16) {
    uint4 v0 = *((const uint4*)(h + (size_t)col[e] * HID) + l32);
    uint4 v1 = *((const uint4*)(h + (size_t)col[e + 2] * HID) + l32);
    uint4 v2 = *((const uint4*)(h + (size_t)col[e + 4] * HID) + l32);
    uint4 v3 = *((const uint4*)(h + (size_t)col[e + 6] * HID) + l32);
    uint4 v4 = *((const uint4*)(h + (size_t)col[e + 8] * HID) + l32);
    uint4 v5 = *((const uint4*)(h + (size_t)col[e + 10] * HID) + l32);
    uint4 v6 = *((const uint4*)(h + (size_t)col[e + 12] * HID) + l32);
    uint4 v7 = *((const uint4*)(h + (size_t)col[e + 14] * HID) + l32);
    acc8(a, v0); acc8(a, v1); acc8(a, v2); acc8(a, v3);
    acc8(a, v4); acc8(a, v5); acc8(a, v6); acc8(a, v7);
  }
  for (; e + 6 < r1; e += 8) {
    uint4 v0 = *((const uint4*)(h + (size_t)col[e] * HID) + l32);
    uint4 v1 = *((const uint4*)(h + (size_t)col[e + 2] * HID) + l32);
    uint4 v2 = *((const uint4*)(h + (size_t)col[e + 4] * HID) + l32);
    uint4 v3 = *((const uint4*)(h + (size_t)col[e + 6] * HID) + l32);
    acc8(a, v0); acc8(a, v1); acc8(a, v2); acc8(a, v3);
  }
  for (; e < r1; e += 2) {
    uint4 v0 = *((const uint4*)(h + (size_t)col[e] * HID) + l32);
    acc8(a, v0);
  }
#pragma unroll
  for (int j = 0; j < 8; j++) a[j] += __shfl_xor(a[j], 32, 64);
  if (half == 0) {
    float inv = inv_cnt[node];
    uint4 o;
    o.x = (unsigned)f2b(a[0] * inv) | ((unsigned)f2b(a[1] * inv) << 16);
    o.y = (unsigned)f2b(a[2] * inv) | ((unsigned)f2b(a[3] * inv) << 16);
    o.z = (unsigned)f2b(a[4] * inv) | ((unsigned)f2b(a[5] * inv) << 16);
    o.w = (unsigned)f2b(a[6] * inv) | ((unsigned)f2b(a[7] * inv) << 16);
    *((uint4*)(aggr + (size_t)node * HID) + l32) = o;
  }
}

// ------------------------------------- MFMA GEMM + fused BN partials --------
// hpre[m][n] = sum_k cat(aggr,h)[m][k] * B[k][n];  B^T given as Wt[n][k].
// 128x256 tile (full N in one block -> A staged ONCE), BK=32,
// 4 waves each 64x128.  Also emits per-block BN column partials (sum, sumsq)
// from the fp32 accumulators (rows >= N_NODES masked out) -> psum[782][512].
__global__ __launch_bounds__(256, 2) void gemm_fused(
    const u16* __restrict__ hb, const u16* __restrict__ aggr,
    const u16* __restrict__ Bt, u16* __restrict__ hpre,
    float* __restrict__ psum) {
  __shared__ u16 As[128 * 32];   // 8 KB
  __shared__ u16 Bs[256 * 32];   // 16 KB
  __shared__ float bns[4][8][16][2];  // 4 KB
  int tid = threadIdx.x;
  int wid = tid >> 6, lane = tid & 63;
  int m0 = blockIdx.x * 128;
  int q = lane >> 4, c = lane & 15;
  int wm = (wid >> 1) * 64, wn = (wid & 1) * 128;

  f32x4 zero = {0.f, 0.f, 0.f, 0.f};
  f32x4 acc[4][8];
#pragma unroll
  for (int mi = 0; mi < 4; mi++)
#pragma unroll
    for (int ni = 0; ni < 8; ni++) acc[mi][ni] = zero;

  // A staging geometry (2 issues/thread)
  int srowA0 = wid * 32 + (lane >> 2);
  int cgA0 = (lane & 3) ^ ((srowA0 >> 1) & 3);
  int srowA1 = srowA0 + 16;
  int cgA1 = (lane & 3) ^ ((srowA1 >> 1) & 3);
  // B staging geometry (4 issues/thread): issue j covers rows j*64 + wid*16 ..+15
  int srowB[4], cgB[4];
#pragma unroll
  for (int j = 0; j < 4; j++) {
    srowB[j] = j * 64 + wid * 16 + (lane >> 2);
    cgB[j] = (lane & 3) ^ ((srowB[j] >> 1) & 3);
  }

  // frag-read LDS offsets (elements), loop-invariant
  int aoff[4], boff[8];
#pragma unroll
  for (int mi = 0; mi < 4; mi++) {
    int row = wm + mi * 16 + c;
    aoff[mi] = row * 32 + ((q ^ ((row >> 1) & 3)) << 3);
  }
#pragma unroll
  for (int ni = 0; ni < 8; ni++) {
    int row = wn + ni * 16 + c;
    boff[ni] = row * 32 + ((q ^ ((row >> 1) & 3)) << 3);
  }

  for (int k0 = 0; k0 < 512; k0 += 32) {
    const u16* Asrc = (k0 < 256) ? aggr : hb;
    int ksrc = k0 & 255;
    gload16(Asrc + ((size_t)(m0 + srowA0) * HID + ksrc + cgA0 * 8), &As[(wid * 32) * 32]);
    gload16(Asrc + ((size_t)(m0 + srowA1) * HID + ksrc + cgA1 * 8), &As[(wid * 32 + 16) * 32]);
#pragma unroll
    for (int j = 0; j < 4; j++)
      gload16(Bt + ((size_t)srowB[j] * 512 + k0 + cgB[j] * 8), &Bs[(j * 64 + wid * 16) * 32]);
    __syncthreads();
    bf16x8 af[4], bfr[8];
#pragma unroll
    for (int mi = 0; mi < 4; mi++) af[mi] = *(const bf16x8*)&As[aoff[mi]];
#pragma unroll
    for (int ni = 0; ni < 8; ni++) bfr[ni] = *(const bf16x8*)&Bs[boff[ni]];
#pragma unroll
    for (int mi = 0; mi < 4; mi++)
#pragma unroll
      for (int ni = 0; ni < 8; ni++)
        acc[mi][ni] = __builtin_amdgcn_mfma_f32_16x16x32_bf16(af[mi], bfr[ni],
                                                              acc[mi][ni], 0, 0, 0);
    __syncthreads();
  }

  // ---- store hpre (C/D layout: col=lane&15, row=(lane>>4)*4+reg) ----
#pragma unroll
  for (int mi = 0; mi < 4; mi++) {
#pragma unroll
    for (int r = 0; r < 4; r++) {
      int gm = m0 + wm + mi * 16 + q * 4 + r;
      if (gm < N_NODES) {
#pragma unroll
        for (int ni = 0; ni < 8; ni++) {
          int gn = wn + ni * 16 + c;
          hpre[(size_t)gm * HID + gn] = f2b(acc[mi][ni][r]);
        }
      }
    }
  }

  // ---- BN column partials from fp32 acc (mask pad rows) ----
#pragma unroll
  for (int ni = 0; ni < 8; ni++) {
    float s = 0.f, s2 = 0.f;
#pragma unroll
    for (int mi = 0; mi < 4; mi++) {
#pragma unroll
      for (int r = 0; r < 4; r++) {
        int gm = m0 + wm + mi * 16 + q * 4 + r;
        float v = (gm < N_NODES) ? acc[mi][ni][r] : 0.f;
        s += v;
        s2 += v * v;
      }
    }
    s += __shfl_xor(s, 16, 64);
    s += __shfl_xor(s, 32, 64);
    s2 += __shfl_xor(s2, 16, 64);
    s2 += __shfl_xor(s2, 32, 64);
    if (q == 0) {
      bns[wid][ni][c][0] = s;
      bns[wid][ni][c][1] = s2;
    }
  }
  __syncthreads();
  {
    int wnh = tid >> 7, ni = (tid >> 4) & 7, cc = tid & 15;
    float s = bns[wnh][ni][cc][0] + bns[wnh + 2][ni][cc][0];
    float s2 = bns[wnh][ni][cc][1] + bns[wnh + 2][ni][cc][1];
    int coln = wnh * 128 + ni * 16 + cc;
    psum[(size_t)blockIdx.x * 512 + coln] = s;
    psum[(size_t)blockIdx.x * 512 + 256 + coln] = s2;
  }
}

// --------------------------------- BN reduce (tree, atomic-free) ------------
#define BN_MID 16
__global__ __launch_bounds__(256) void bn_mid(const float* __restrict__ psum,
                                              float* __restrict__ tmp) {
  int b = blockIdx.x;
  int f = threadIdx.x;
  int mb0 = b * 49;
  int mb1 = min(mb0 + 49, N_MBLK);
  float s = 0.f, s2 = 0.f;
  for (int mb = mb0; mb < mb1; mb++) {
    s += psum[(size_t)mb * 512 + f];
    s2 += psum[(size_t)mb * 512 + 256 + f];
  }
  tmp[(size_t)b * 512 + f] = s;
  tmp[(size_t)b * 512 + 256 + f] = s2;
}

__global__ void bn_fin(const float* __restrict__ tmp,
                       const float* __restrict__ gamma,
                       const float* __restrict__ beta,
                       float* __restrict__ ss) {
  int f = threadIdx.x;
  float sum = 0.f, sq = 0.f;
#pragma unroll
  for (int b = 0; b < BN_MID; b++) {
    sum += tmp[(size_t)b * 512 + f];
    sq += tmp[(size_t)b * 512 + 256 + f];
  }
  const float invN = 1.0f / (float)N_NODES;
  float mu = sum * invN;
  float ex2 = sq * invN;
  float var = fmaxf(ex2 - mu * mu, 0.f);
  float sc = gamma[f] * rsqrtf(var + 1e-5f);
  ss[f] = sc;
  ss[HID + f] = beta[f] - mu * sc;
}

__global__ __launch_bounds__(256) void bn_apply_bf16(const uint4* __restrict__ hpre,
                                                     const float* __restrict__ ss,
                                                     uint4* __restrict__ hout) {
  int idx0 = blockIdx.x * blockDim.x + threadIdx.x;
  int cb = (idx0 & 31) * 8;  // column base (row = 32 uint4)
  float sc[8], sh[8];
#pragma unroll
  for (int j = 0; j < 8; j++) { sc[j] = ss[cb + j]; sh[j] = ss[HID + cb + j]; }
  const int total = N_NODES * 32;
  const int step = gridDim.x * blockDim.x;  // 524288, multiple of 32
  for (int i = idx0; i < total; i += step) {
    uint4 v = hpre[i];
    unsigned vv[4] = {v.x, v.y, v.z, v.w};
    unsigned o[4];
#pragma unroll
    for (int j = 0; j < 4; j++) {
      float lo = b2f_lo(vv[j]);
      float hi = b2f_hi(vv[j]);
      lo = fmaxf(fmaf(lo, sc[2 * j], sh[2 * j]), 0.f);
      hi = fmaxf(fmaf(hi, sc[2 * j + 1], sh[2 * j + 1]), 0.f);
      o[j] = (unsigned)f2b(lo) | ((unsigned)f2b(hi) << 16);
    }
    uint4 ov = {o[0], o[1], o[2], o[3]};
    hout[i] = ov;
  }
}

// ----------------------------- pool + MLP (fused, one block/graph) ----------
__global__ __launch_bounds__(256) void pool_mlp(
    const u16* __restrict__ h, const int* __restrict__ batch,
    const float* __restrict__ W1, const float* __restrict__ b1,
    const float* __restrict__ W2, const float* __restrict__ b2,
    float* __restrict__ out) {
  __shared__ float red[256][9];
  __shared__ float gs[HID];
  __shared__ float ts[HID];
  __shared__ float rn[PROJ];
  int g = blockIdx.x;
  int t = threadIdx.x;
  // row range of graph g in sorted batch: [lo, hi)
  int a = 0, b = N_NODES;
  while (a < b) { int m = (a + b) >> 1; if (batch[m] < g) a = m + 1; else b = m; }
  int lo = a;
  b = N_NODES;
  while (a < b) { int m = (a + b) >> 1; if (batch[m] < g + 1) a = m + 1; else b = m; }
  int hi = a;

  int rs = t >> 5, c = t & 31;
  float acc[8] = {0.f, 0.f, 0.f, 0.f, 0.f, 0.f, 0.f, 0.f};
  for (int r = lo + rs; r < hi; r += 8) {
    uint4 v = *((const uint4*)(h + (size_t)r * HID) + c);
    acc8(acc, v);
  }
#pragma unroll
  for (int j = 0; j < 8; j++) red[t][j] = acc[j];
  __syncthreads();
  int cc = t >> 3, j = t & 7;
  float sum = 0.f;
#pragma unroll
  for (int k = 0; k < 8; k++) sum += red[k * 32 + cc][j];
  float inv = 1.0f / fmaxf((float)(hi - lo), 1.0f);
  gs[t] = sum * inv;
  __syncthreads();

  float s = b1[t];
  for (int k = 0; k < HID; k++) s = fmaf(gs[k], W1[(size_t)k * HID + t], s);
  ts[t] = fmaxf(s, 0.f);
  __syncthreads();
  float z = 0.f;
  if (t < PROJ) {
    z = b2[t];
    for (int k = 0; k < HID; k++) z = fmaf(ts[k], W2[(size_t)k * PROJ + t], z);
    rn[t] = z * z;
  }
  __syncthreads();
  for (int off = PROJ / 2; off > 0; off >>= 1) {
    if (t < off) rn[t] += rn[t + off];
    __syncthreads();
  }
  float norm = fmaxf(sqrtf(rn[0]), 1e-12f);
  if (t < PROJ) out[(size_t)g * PROJ + t] = z / norm;
}

// --------------------------------------------------------------- launch -----
extern "C" void kernel_launch(void* const* d_in, const int* in_sizes, int n_in,
                              void* d_out, int out_size, void* d_ws, size_t ws_size,
                              hipStream_t stream) {
  const float* x = (const float*)d_in[0];
  const int* ei = (const int*)d_in[1];
  const int* src = ei;
  const int* dst = ei + N_EDGES;
  const int* batch = (const int*)d_in[2];
  const float* Wl = (const float*)d_in[3];
  // d_in[4] = bl: per-column bias is exactly cancelled by BatchNorm -> unused
  const float* Wr = (const float*)d_in[5];
  const float* gamma = (const float*)d_in[6];
  const float* beta = (const float*)d_in[7];
  const float* W1 = (const float*)d_in[8];
  const float* b1 = (const float*)d_in[9];
  const float* W2 = (const float*)d_in[10];
  const float* b2 = (const float*)d_in[11];
  float* out = (float*)d_out;

  char* p = (char*)d_ws;
  const size_t HB = (size_t)M_PAD * HID * sizeof(u16);  // 51.25 MB
  u16* hb0 = (u16*)p;    p += HB;
  u16* hb1 = (u16*)p;    p += HB;
  u16* aggr = (u16*)p;   p += HB;
  u16* hpre = (u16*)p;   p += HB;
  u16* Wt = (u16*)p;     p += (size_t)NLAYERS * 512 * HID * sizeof(u16);  // 1 MB
  int* col = (int*)p;    p += (size_t)N_EDGES * sizeof(int);              // 6.4 MB
  int* row_ptr = (int*)p; p += 400016;
  float* inv_cnt = (float*)p; p += (size_t)N_NODES * sizeof(float);
  float* psum = (float*)p;    p += (size_t)N_MBLK * 512 * sizeof(float);  // 1.6 MB
  float* tmp = (float*)p;     p += (size_t)BN_MID * 512 * sizeof(float);
  float* ss = (float*)p;      p += 512 * sizeof(float);
  int* bsum = (int*)p;        p += 128 * sizeof(int);
  int* boff = (int*)p;        p += 128 * sizeof(int);

  // transient CSR-build arrays overlaid into hpre (first written in layer-0 gemm)
  int* counts = (int*)hpre;
  int* fill = counts + N_NODES;

  // ---- build CSR (once; edge_index is layer-invariant) ----
  hipMemsetAsync(counts, 0, 2 * (size_t)N_NODES * sizeof(int), stream);
  count_kernel<<<(N_EDGES + 255) / 256, 256, 0, stream>>>(dst, counts);
  inv_kernel<<<(N_NODES + 255) / 256, 256, 0, stream>>>(counts, inv_cnt);
  scan_partial<<<N_SCAN_BLOCKS, 256, 0, stream>>>(counts, bsum);
  scan_bsums<<<1, 128, 0, stream>>>(bsum, boff);
  scan_final<<<N_SCAN_BLOCKS, 256, 0, stream>>>(counts, boff, row_ptr);
  fill_kernel<<<(N_EDGES + 255) / 256, 256, 0, stream>>>(src, dst, row_ptr, fill, col);

  // ---- one-time converts ----
  convert_x<<<N_NODES / 4, 256, 0, stream>>>((const float4*)x, (ushort4*)hb0);
  convert_w<<<(NLAYERS * 512 * HID) / 256, 256, 0, stream>>>(Wl, Wr, Wt);

  u16* hcur = hb0;
  u16* hnext = hb1;
  for (int l = 0; l < NLAYERS; l++) {
    aggregate_bf16<<<N_NODES / 4, 256, 0, stream>>>(hcur, row_ptr, col, inv_cnt, aggr);
    gemm_fused<<<N_MBLK, 256, 0, stream>>>(hcur, aggr, Wt + (size_t)l * 512 * HID,
                                           hpre, psum);
    bn_mid<<<BN_MID, 256, 0, stream>>>(psum, tmp);
    bn_fin<<<1, 256, 0, stream>>>(tmp, gamma + (size_t)l * HID,
                                  beta + (size_t)l * HID, ss);
    bn_apply_bf16<<<2048, 256, 0, stream>>>((const uint4*)hpre, ss, (uint4*)hnext);
    u16* t = hcur; hcur = hnext; hnext = t;
  }

  pool_mlp<<<N_GRAPHS, 256, 0, stream>>>(hcur, batch, W1, b1, W2, b2, out);
}

// Round 8
// 1162.539 us; speedup vs baseline: 1.6128x; 1.0220x over previous
//
#include <hip/hip_runtime.h>

#define N_NODES 100000
#define M_PAD   100096   // 782 * 128
#define N_MBLK  782
#define N_EDGES 1600000
#define N_GRAPHS 64
#define HID 256
#define PROJ 128
#define NLAYERS 4

typedef unsigned short u16;
typedef __attribute__((ext_vector_type(8))) short bf16x8;
typedef __attribute__((ext_vector_type(4))) float f32x4;

__device__ __forceinline__ float b2f(u16 u) {
  return __uint_as_float(((unsigned)u) << 16);
}
__device__ __forceinline__ float b2f_lo(unsigned u) {
  return __uint_as_float(u << 16);
}
__device__ __forceinline__ float b2f_hi(unsigned u) {
  return __uint_as_float(u & 0xFFFF0000u);
}
__device__ __forceinline__ u16 f2b(float f) {
  unsigned u = __float_as_uint(f);
  u = (u + 0x7FFF + ((u >> 16) & 1)) >> 16;  // round-to-nearest-even
  return (u16)u;
}
__device__ __forceinline__ void gload16(const void* g, void* l) {
  __builtin_amdgcn_global_load_lds((const __attribute__((address_space(1))) void*)g,
                                   (__attribute__((address_space(3))) void*)l, 16, 0, 0);
}
__device__ __forceinline__ void acc8(float* a, const uint4& v) {
  a[0] += b2f_lo(v.x); a[1] += b2f_hi(v.x);
  a[2] += b2f_lo(v.y); a[3] += b2f_hi(v.y);
  a[4] += b2f_lo(v.z); a[5] += b2f_hi(v.z);
  a[6] += b2f_lo(v.w); a[7] += b2f_hi(v.w);
}

// ---------------------------------------------------------------- CSR -------
__global__ void count_kernel(const int* __restrict__ dst, int* __restrict__ cnt) {
  int e = blockIdx.x * blockDim.x + threadIdx.x;
  if (e < N_EDGES) atomicAdd(&cnt[dst[e]], 1);
}

__global__ void inv_kernel(const int* __restrict__ cnt, float* __restrict__ inv) {
  int n = blockIdx.x * blockDim.x + threadIdx.x;
  if (n < N_NODES) inv[n] = 1.0f / fmaxf((float)cnt[n], 1.0f);
}

#define SCAN_BLK 1024
#define N_SCAN_BLOCKS ((N_NODES + SCAN_BLK - 1) / SCAN_BLK)  // 98

__global__ __launch_bounds__(256) void scan_partial(const int* __restrict__ cnt,
                                                    int* __restrict__ bsum) {
  __shared__ int red[256];
  int t = threadIdx.x;
  int base = blockIdx.x * SCAN_BLK + t * 4;
  int s = 0;
#pragma unroll
  for (int j = 0; j < 4; j++) {
    int i = base + j;
    if (i < N_NODES) s += cnt[i];
  }
  red[t] = s;
  __syncthreads();
  for (int off = 128; off > 0; off >>= 1) {
    if (t < off) red[t] += red[t + off];
    __syncthreads();
  }
  if (t == 0) bsum[blockIdx.x] = red[0];
}

__global__ __launch_bounds__(128) void scan_bsums(const int* __restrict__ bsum,
                                                  int* __restrict__ boff) {
  __shared__ int tile[128];
  int t = threadIdx.x;
  int v = (t < N_SCAN_BLOCKS) ? bsum[t] : 0;
  tile[t] = v;
  __syncthreads();
#pragma unroll
  for (int off = 1; off < 128; off <<= 1) {
    int add = (t >= off) ? tile[t - off] : 0;
    __syncthreads();
    tile[t] += add;
    __syncthreads();
  }
  if (t < N_SCAN_BLOCKS) boff[t] = tile[t] - v;  // exclusive
}

__global__ __launch_bounds__(256) void scan_final(const int* __restrict__ cnt,
                                                  const int* __restrict__ boff,
                                                  int* __restrict__ row_ptr) {
  __shared__ int tsum[256];
  int t = threadIdx.x;
  int base = blockIdx.x * SCAN_BLK + t * 4;
  int v[4];
  int s = 0;
#pragma unroll
  for (int j = 0; j < 4; j++) {
    int i = base + j;
    v[j] = (i < N_NODES) ? cnt[i] : 0;
    s += v[j];
  }
  tsum[t] = s;
  __syncthreads();
#pragma unroll
  for (int off = 1; off < 256; off <<= 1) {
    int add = (t >= off) ? tsum[t - off] : 0;
    __syncthreads();
    tsum[t] += add;
    __syncthreads();
  }
  int excl = tsum[t] - s + boff[blockIdx.x];
#pragma unroll
  for (int j = 0; j < 4; j++) {
    int i = base + j;
    if (i < N_NODES) {
      row_ptr[i] = excl;
      excl += v[j];
    }
  }
  if (blockIdx.x == 0 && t == 0) row_ptr[N_NODES] = N_EDGES;
}

__global__ void fill_kernel(const int* __restrict__ src, const int* __restrict__ dst,
                            const int* __restrict__ row_ptr, int* __restrict__ fill,
                            int* __restrict__ col) {
  int e = blockIdx.x * blockDim.x + threadIdx.x;
  if (e < N_EDGES) {
    int d = dst[e];
    int pos = row_ptr[d] + atomicAdd(&fill[d], 1);
    col[pos] = src[e];
  }
}

// ------------------------------------------------------------ converts ------
__global__ __launch_bounds__(256) void convert_x(const float4* __restrict__ x,
                                                 ushort4* __restrict__ hb) {
  int i = blockIdx.x * blockDim.x + threadIdx.x;  // exactly N_NODES*64 threads
  float4 v = x[i];
  ushort4 o;
  o.x = f2b(v.x); o.y = f2b(v.y); o.z = f2b(v.z); o.w = f2b(v.w);
  hb[i] = o;
}

// Wt[l][n][k] bf16, k<256 -> Wl[l][k][n], k>=256 -> Wr[l][k-256][n]
__global__ __launch_bounds__(256) void convert_w(const float* __restrict__ Wl,
                                                 const float* __restrict__ Wr,
                                                 u16* __restrict__ Wt) {
  int idx = blockIdx.x * blockDim.x + threadIdx.x;  // 4*256*512 threads
  int l = idx >> 17;
  int r = idx & ((1 << 17) - 1);
  int n = r >> 9;
  int k = r & 511;
  float v = (k < 256) ? Wl[(size_t)l * 65536 + k * 256 + n]
                      : Wr[(size_t)l * 65536 + (k - 256) * 256 + n];
  Wt[idx] = f2b(v);
}

// ----------------------------------------------------------- aggregation ----
// one wave per node; two 32-lane halves process alternating edges with 16B loads;
// 4 gathers in flight per half (VGPR 28 / high occupancy); shfl_xor(32) merge.
__global__ __launch_bounds__(256) void aggregate_bf16(
    const u16* __restrict__ h, const int* __restrict__ row_ptr,
    const int* __restrict__ col, const float* __restrict__ inv_cnt,
    u16* __restrict__ aggr) {
  int node = blockIdx.x * 4 + (threadIdx.x >> 6);
  int lane = threadIdx.x & 63;
  int half = lane >> 5, l32 = lane & 31;
  int r0 = row_ptr[node], r1 = row_ptr[node + 1];
  float a[8] = {0.f, 0.f, 0.f, 0.f, 0.f, 0.f, 0.f, 0.f};
  int e = r0 + half;
  for (; e + 6 < r1; e += 8) {
    int s0 = col[e], s1 = col[e + 2], s2 = col[e + 4], s3 = col[e + 6];
    uint4 v0 = *((const uint4*)(h + (size_t)s0 * HID) + l32);
    uint4 v1 = *((const uint4*)(h + (size_t)s1 * HID) + l32);
    uint4 v2 = *((const uint4*)(h + (size_t)s2 * HID) + l32);
    uint4 v3 = *((const uint4*)(h + (size_t)s3 * HID) + l32);
    acc8(a, v0); acc8(a, v1); acc8(a, v2); acc8(a, v3);
  }
  for (; e < r1; e += 2) {
    int s0 = col[e];
    uint4 v0 = *((const uint4*)(h + (size_t)s0 * HID) + l32);
    acc8(a, v0);
  }
#pragma unroll
  for (int j = 0; j < 8; j++) a[j] += __shfl_xor(a[j], 32, 64);
  if (half == 0) {
    float inv = inv_cnt[node];
    uint4 o;
    o.x = (unsigned)f2b(a[0] * inv) | ((unsigned)f2b(a[1] * inv) << 16);
    o.y = (unsigned)f2b(a[2] * inv) | ((unsigned)f2b(a[3] * inv) << 16);
    o.z = (unsigned)f2b(a[4] * inv) | ((unsigned)f2b(a[5] * inv) << 16);
    o.w = (unsigned)f2b(a[6] * inv) | ((unsigned)f2b(a[7] * inv) << 16);
    *((uint4*)(aggr + (size_t)node * HID) + l32) = o;
  }
}

// ------------------------------------- MFMA GEMM + fused BN partials --------
// hpre[m][n] = sum_k cat(aggr,h)[m][k] * B[k][n];  B^T given as Wt[n][k].
// 128x256 tile, BK=32, 4 waves each 64x128.  Epilogue: LDS-transposed
// coalesced uint4 C-stores (was 128 global_store_short/thread) + per-block
// BN column partials from the fp32 accumulators -> psum[782][512].
__global__ __launch_bounds__(256, 2) void gemm_fused(
    const u16* __restrict__ hb, const u16* __restrict__ aggr,
    const u16* __restrict__ Bt, u16* __restrict__ hpre,
    float* __restrict__ psum) {
  __shared__ u16 smem[128 * 32 + 256 * 32];  // 24 KB: staging; reused as epilogue buf
  __shared__ float bns[4][8][16][2];         // 4 KB
  u16* As = smem;
  u16* Bs = smem + 128 * 32;
  u16* ep = smem;  // 32 rows x 256 cols bf16 = 16 KB (used after final K-loop sync)

  int tid = threadIdx.x;
  int wid = tid >> 6, lane = tid & 63;
  int m0 = blockIdx.x * 128;
  int q = lane >> 4, c = lane & 15;
  int wm = (wid >> 1) * 64, wn = (wid & 1) * 128;

  f32x4 zero = {0.f, 0.f, 0.f, 0.f};
  f32x4 acc[4][8];
#pragma unroll
  for (int mi = 0; mi < 4; mi++)
#pragma unroll
    for (int ni = 0; ni < 8; ni++) acc[mi][ni] = zero;

  // A staging geometry (2 issues/thread)
  int srowA0 = wid * 32 + (lane >> 2);
  int cgA0 = (lane & 3) ^ ((srowA0 >> 1) & 3);
  int srowA1 = srowA0 + 16;
  int cgA1 = (lane & 3) ^ ((srowA1 >> 1) & 3);
  // B staging geometry (4 issues/thread)
  int srowB[4], cgB[4];
#pragma unroll
  for (int j = 0; j < 4; j++) {
    srowB[j] = j * 64 + wid * 16 + (lane >> 2);
    cgB[j] = (lane & 3) ^ ((srowB[j] >> 1) & 3);
  }

  // frag-read LDS offsets (elements), loop-invariant
  int aoff[4], boff[8];
#pragma unroll
  for (int mi = 0; mi < 4; mi++) {
    int row = wm + mi * 16 + c;
    aoff[mi] = row * 32 + ((q ^ ((row >> 1) & 3)) << 3);
  }
#pragma unroll
  for (int ni = 0; ni < 8; ni++) {
    int row = wn + ni * 16 + c;
    boff[ni] = row * 32 + ((q ^ ((row >> 1) & 3)) << 3);
  }

  for (int k0 = 0; k0 < 512; k0 += 32) {
    const u16* Asrc = (k0 < 256) ? aggr : hb;
    int ksrc = k0 & 255;
    gload16(Asrc + ((size_t)(m0 + srowA0) * HID + ksrc + cgA0 * 8), &As[(wid * 32) * 32]);
    gload16(Asrc + ((size_t)(m0 + srowA1) * HID + ksrc + cgA1 * 8), &As[(wid * 32 + 16) * 32]);
#pragma unroll
    for (int j = 0; j < 4; j++)
      gload16(Bt + ((size_t)srowB[j] * 512 + k0 + cgB[j] * 8), &Bs[(j * 64 + wid * 16) * 32]);
    __syncthreads();
    bf16x8 af[4], bfr[8];
#pragma unroll
    for (int mi = 0; mi < 4; mi++) af[mi] = *(const bf16x8*)&As[aoff[mi]];
#pragma unroll
    for (int ni = 0; ni < 8; ni++) bfr[ni] = *(const bf16x8*)&Bs[boff[ni]];
#pragma unroll
    for (int mi = 0; mi < 4; mi++)
#pragma unroll
      for (int ni = 0; ni < 8; ni++)
        acc[mi][ni] = __builtin_amdgcn_mfma_f32_16x16x32_bf16(af[mi], bfr[ni],
                                                              acc[mi][ni], 0, 0, 0);
    __syncthreads();
  }

  // ---- coalesced C-store: 4 slabs of 32 rows via LDS transpose ----
  // C/D layout: col = wn + ni*16 + c, row(within 16) = q*4 + r
  int rh = wid >> 1;  // row half (0: rows 0-63, 1: rows 64-127)
#pragma unroll
  for (int mi = 0; mi < 4; mi++) {
#pragma unroll
    for (int r = 0; r < 4; r++) {
      int r16 = q * 4 + r;
#pragma unroll
      for (int ni = 0; ni < 8; ni++)
        ep[(rh * 16 + r16) * 256 + wn + ni * 16 + c] = f2b(acc[mi][ni][r]);
    }
    __syncthreads();
    int u = tid;
#pragma unroll
    for (int j = 0; j < 4; j++, u += 256) {
      int lr = u >> 5;     // 0..31 local row
      int cu = u & 31;     // uint4 column
      int gm = m0 + (lr >> 4) * 64 + mi * 16 + (lr & 15);
      if (gm < N_NODES)
        ((uint4*)(hpre + (size_t)gm * HID))[cu] = ((const uint4*)ep)[u];
    }
    __syncthreads();
  }

  // ---- BN column partials from fp32 acc (mask pad rows) ----
#pragma unroll
  for (int ni = 0; ni < 8; ni++) {
    float s = 0.f, s2 = 0.f;
#pragma unroll
    for (int mi = 0; mi < 4; mi++) {
#pragma unroll
      for (int r = 0; r < 4; r++) {
        int gm = m0 + wm + mi * 16 + q * 4 + r;
        float v = (gm < N_NODES) ? acc[mi][ni][r] : 0.f;
        s += v;
        s2 += v * v;
      }
    }
    s += __shfl_xor(s, 16, 64);
    s += __shfl_xor(s, 32, 64);
    s2 += __shfl_xor(s2, 16, 64);
    s2 += __shfl_xor(s2, 32, 64);
    if (q == 0) {
      bns[wid][ni][c][0] = s;
      bns[wid][ni][c][1] = s2;
    }
  }
  __syncthreads();
  {
    int wnh = tid >> 7, ni = (tid >> 4) & 7, cc = tid & 15;
    float s = bns[wnh][ni][cc][0] + bns[wnh + 2][ni][cc][0];
    float s2 = bns[wnh][ni][cc][1] + bns[wnh + 2][ni][cc][1];
    int coln = wnh * 128 + ni * 16 + cc;
    psum[(size_t)blockIdx.x * 512 + coln] = s;
    psum[(size_t)blockIdx.x * 512 + 256 + coln] = s2;
  }
}

// --------------------------------- BN reduce (tree, atomic-free) ------------
#define BN_MID 16
__global__ __launch_bounds__(256) void bn_mid(const float* __restrict__ psum,
                                              float* __restrict__ tmp) {
  int b = blockIdx.x;
  int f = threadIdx.x;
  int mb0 = b * 49;
  int mb1 = min(mb0 + 49, N_MBLK);
  float s = 0.f, s2 = 0.f;
  for (int mb = mb0; mb < mb1; mb++) {
    s += psum[(size_t)mb * 512 + f];
    s2 += psum[(size_t)mb * 512 + 256 + f];
  }
  tmp[(size_t)b * 512 + f] = s;
  tmp[(size_t)b * 512 + 256 + f] = s2;
}

__global__ void bn_fin(const float* __restrict__ tmp,
                       const float* __restrict__ gamma,
                       const float* __restrict__ beta,
                       float* __restrict__ ss) {
  int f = threadIdx.x;
  float sum = 0.f, sq = 0.f;
#pragma unroll
  for (int b = 0; b < BN_MID; b++) {
    sum += tmp[(size_t)b * 512 + f];
    sq += tmp[(size_t)b * 512 + 256 + f];
  }
  const float invN = 1.0f / (float)N_NODES;
  float mu = sum * invN;
  float ex2 = sq * invN;
  float var = fmaxf(ex2 - mu * mu, 0.f);
  float sc = gamma[f] * rsqrtf(var + 1e-5f);
  ss[f] = sc;
  ss[HID + f] = beta[f] - mu * sc;
}

__global__ __launch_bounds__(256) void bn_apply_bf16(const uint4* __restrict__ hpre,
                                                     const float* __restrict__ ss,
                                                     uint4* __restrict__ hout) {
  int idx0 = blockIdx.x * blockDim.x + threadIdx.x;
  int cb = (idx0 & 31) * 8;  // column base (row = 32 uint4)
  float sc[8], sh[8];
#pragma unroll
  for (int j = 0; j < 8; j++) { sc[j] = ss[cb + j]; sh[j] = ss[HID + cb + j]; }
  const int total = N_NODES * 32;
  const int step = gridDim.x * blockDim.x;  // 524288, multiple of 32
  for (int i = idx0; i < total; i += step) {
    uint4 v = hpre[i];
    unsigned vv[4] = {v.x, v.y, v.z, v.w};
    unsigned o[4];
#pragma unroll
    for (int j = 0; j < 4; j++) {
      float lo = b2f_lo(vv[j]);
      float hi = b2f_hi(vv[j]);
      lo = fmaxf(fmaf(lo, sc[2 * j], sh[2 * j]), 0.f);
      hi = fmaxf(fmaf(hi, sc[2 * j + 1], sh[2 * j + 1]), 0.f);
      o[j] = (unsigned)f2b(lo) | ((unsigned)f2b(hi) << 16);
    }
    uint4 ov = {o[0], o[1], o[2], o[3]};
    hout[i] = ov;
  }
}

// ------------- pool + MLP (fused; applies layer-3 BN+ReLU inline) -----------
__global__ __launch_bounds__(256) void pool_mlp(
    const u16* __restrict__ hpre, const float* __restrict__ ss,
    const int* __restrict__ batch,
    const float* __restrict__ W1, const float* __restrict__ b1,
    const float* __restrict__ W2, const float* __restrict__ b2,
    float* __restrict__ out) {
  __shared__ float red[256][9];
  __shared__ float gs[HID];
  __shared__ float ts[HID];
  __shared__ float rn[PROJ];
  int g = blockIdx.x;
  int t = threadIdx.x;
  // row range of graph g in sorted batch: [lo, hi)
  int a = 0, b = N_NODES;
  while (a < b) { int m = (a + b) >> 1; if (batch[m] < g) a = m + 1; else b = m; }
  int lo = a;
  b = N_NODES;
  while (a < b) { int m = (a + b) >> 1; if (batch[m] < g + 1) a = m + 1; else b = m; }
  int hi = a;

  int rs = t >> 5, c = t & 31;
  int cb = c * 8;
  float scv[8], shv[8];
#pragma unroll
  for (int j = 0; j < 8; j++) { scv[j] = ss[cb + j]; shv[j] = ss[HID + cb + j]; }
  float acc[8] = {0.f, 0.f, 0.f, 0.f, 0.f, 0.f, 0.f, 0.f};
  for (int r = lo + rs; r < hi; r += 8) {
    uint4 v = *((const uint4*)(hpre + (size_t)r * HID) + c);
    unsigned vv[4] = {v.x, v.y, v.z, v.w};
#pragma unroll
    for (int j = 0; j < 4; j++) {
      acc[2 * j]     += fmaxf(fmaf(b2f_lo(vv[j]), scv[2 * j], shv[2 * j]), 0.f);
      acc[2 * j + 1] += fmaxf(fmaf(b2f_hi(vv[j]), scv[2 * j + 1], shv[2 * j + 1]), 0.f);
    }
  }
#pragma unroll
  for (int j = 0; j < 8; j++) red[t][j] = acc[j];
  __syncthreads();
  int cc = t >> 3, j = t & 7;
  float sum = 0.f;
#pragma unroll
  for (int k = 0; k < 8; k++) sum += red[k * 32 + cc][j];
  float inv = 1.0f / fmaxf((float)(hi - lo), 1.0f);
  gs[t] = sum * inv;
  __syncthreads();

  float s = b1[t];
  for (int k = 0; k < HID; k++) s = fmaf(gs[k], W1[(size_t)k * HID + t], s);
  ts[t] = fmaxf(s, 0.f);
  __syncthreads();
  float z = 0.f;
  if (t < PROJ) {
    z = b2[t];
    for (int k = 0; k < HID; k++) z = fmaf(ts[k], W2[(size_t)k * PROJ + t], z);
    rn[t] = z * z;
  }
  __syncthreads();
  for (int off = PROJ / 2; off > 0; off >>= 1) {
    if (t < off) rn[t] += rn[t + off];
    __syncthreads();
  }
  float norm = fmaxf(sqrtf(rn[0]), 1e-12f);
  if (t < PROJ) out[(size_t)g * PROJ + t] = z / norm;
}

// --------------------------------------------------------------- launch -----
extern "C" void kernel_launch(void* const* d_in, const int* in_sizes, int n_in,
                              void* d_out, int out_size, void* d_ws, size_t ws_size,
                              hipStream_t stream) {
  const float* x = (const float*)d_in[0];
  const int* ei = (const int*)d_in[1];
  const int* src = ei;
  const int* dst = ei + N_EDGES;
  const int* batch = (const int*)d_in[2];
  const float* Wl = (const float*)d_in[3];
  // d_in[4] = bl: per-column bias is exactly cancelled by BatchNorm -> unused
  const float* Wr = (const float*)d_in[5];
  const float* gamma = (const float*)d_in[6];
  const float* beta = (const float*)d_in[7];
  const float* W1 = (const float*)d_in[8];
  const float* b1 = (const float*)d_in[9];
  const float* W2 = (const float*)d_in[10];
  const float* b2 = (const float*)d_in[11];
  float* out = (float*)d_out;

  char* p = (char*)d_ws;
  const size_t HB = (size_t)M_PAD * HID * sizeof(u16);  // 51.25 MB
  u16* hb0 = (u16*)p;    p += HB;
  u16* hb1 = (u16*)p;    p += HB;
  u16* aggr = (u16*)p;   p += HB;
  u16* hpre = (u16*)p;   p += HB;
  u16* Wt = (u16*)p;     p += (size_t)NLAYERS * 512 * HID * sizeof(u16);  // 1 MB
  int* col = (int*)p;    p += (size_t)N_EDGES * sizeof(int);              // 6.4 MB
  int* row_ptr = (int*)p; p += 400016;
  float* inv_cnt = (float*)p; p += (size_t)N_NODES * sizeof(float);
  float* psum = (float*)p;    p += (size_t)N_MBLK * 512 * sizeof(float);  // 1.6 MB
  float* tmp = (float*)p;     p += (size_t)BN_MID * 512 * sizeof(float);
  float* ss = (float*)p;      p += 512 * sizeof(float);
  int* bsum = (int*)p;        p += 128 * sizeof(int);
  int* boff = (int*)p;        p += 128 * sizeof(int);

  // transient CSR-build arrays overlaid into hpre (first written in layer-0 gemm)
  int* counts = (int*)hpre;
  int* fill = counts + N_NODES;

  // ---- build CSR (once; edge_index is layer-invariant) ----
  hipMemsetAsync(counts, 0, 2 * (size_t)N_NODES * sizeof(int), stream);
  count_kernel<<<(N_EDGES + 255) / 256, 256, 0, stream>>>(dst, counts);
  inv_kernel<<<(N_NODES + 255) / 256, 256, 0, stream>>>(counts, inv_cnt);
  scan_partial<<<N_SCAN_BLOCKS, 256, 0, stream>>>(counts, bsum);
  scan_bsums<<<1, 128, 0, stream>>>(bsum, boff);
  scan_final<<<N_SCAN_BLOCKS, 256, 0, stream>>>(counts, boff, row_ptr);
  fill_kernel<<<(N_EDGES + 255) / 256, 256, 0, stream>>>(src, dst, row_ptr, fill, col);

  // ---- one-time converts ----
  convert_x<<<N_NODES / 4, 256, 0, stream>>>((const float4*)x, (ushort4*)hb0);
  convert_w<<<(NLAYERS * 512 * HID) / 256, 256, 0, stream>>>(Wl, Wr, Wt);

  u16* hcur = hb0;
  u16* hnext = hb1;
  for (int l = 0; l < NLAYERS; l++) {
    aggregate_bf16<<<N_NODES / 4, 256, 0, stream>>>(hcur, row_ptr, col, inv_cnt, aggr);
    gemm_fused<<<N_MBLK, 256, 0, stream>>>(hcur, aggr, Wt + (size_t)l * 512 * HID,
                                           hpre, psum);
    bn_mid<<<BN_MID, 256, 0, stream>>>(psum, tmp);
    bn_fin<<<1, 256, 0, stream>>>(tmp, gamma + (size_t)l * HID,
                                  beta + (size_t)l * HID, ss);
    if (l < NLAYERS - 1) {
      bn_apply_bf16<<<2048, 256, 0, stream>>>((const uint4*)hpre, ss, (uint4*)hnext);
      u16* t = hcur; hcur = hnext; hnext = t;
    }
  }

  // layer-3 BN+ReLU fused into pooling (reads hpre + ss)
  pool_mlp<<<N_GRAPHS, 256, 0, stream>>>(hpre, ss, batch, W1, b1, W2, b2, out);
}

// Round 9
// 1125.733 us; speedup vs baseline: 1.6655x; 1.0327x over previous
//
#include <hip/hip_runtime.h>

#define N_NODES 100000
#define M_PAD   100096   // 782 * 128
#define N_MBLK  782
#define N_EDGES 1600000
#define N_GRAPHS 64
#define HID 256
#define PROJ 128
#define NLAYERS 4

typedef unsigned short u16;
typedef __attribute__((ext_vector_type(8))) short bf16x8;
typedef __attribute__((ext_vector_type(4))) float f32x4;

__device__ __forceinline__ float b2f(u16 u) {
  return __uint_as_float(((unsigned)u) << 16);
}
__device__ __forceinline__ float b2f_lo(unsigned u) {
  return __uint_as_float(u << 16);
}
__device__ __forceinline__ float b2f_hi(unsigned u) {
  return __uint_as_float(u & 0xFFFF0000u);
}
__device__ __forceinline__ u16 f2b(float f) {
  unsigned u = __float_as_uint(f);
  u = (u + 0x7FFF + ((u >> 16) & 1)) >> 16;  // round-to-nearest-even
  return (u16)u;
}
__device__ __forceinline__ void gload16(const void* g, void* l) {
  __builtin_amdgcn_global_load_lds((const __attribute__((address_space(1))) void*)g,
                                   (__attribute__((address_space(3))) void*)l, 16, 0, 0);
}
__device__ __forceinline__ void acc8(float* a, const uint4& v) {
  a[0] += b2f_lo(v.x); a[1] += b2f_hi(v.x);
  a[2] += b2f_lo(v.y); a[3] += b2f_hi(v.y);
  a[4] += b2f_lo(v.z); a[5] += b2f_hi(v.z);
  a[6] += b2f_lo(v.w); a[7] += b2f_hi(v.w);
}

// ---------------------------------------------------------------- CSR -------
__global__ void count_kernel(const int* __restrict__ dst, int* __restrict__ cnt) {
  int e = blockIdx.x * blockDim.x + threadIdx.x;
  if (e < N_EDGES) atomicAdd(&cnt[dst[e]], 1);
}

__global__ void inv_kernel(const int* __restrict__ cnt, float* __restrict__ inv) {
  int n = blockIdx.x * blockDim.x + threadIdx.x;
  if (n < N_NODES) inv[n] = 1.0f / fmaxf((float)cnt[n], 1.0f);
}

#define SCAN_BLK 1024
#define N_SCAN_BLOCKS ((N_NODES + SCAN_BLK - 1) / SCAN_BLK)  // 98

__global__ __launch_bounds__(256) void scan_partial(const int* __restrict__ cnt,
                                                    int* __restrict__ bsum) {
  __shared__ int red[256];
  int t = threadIdx.x;
  int base = blockIdx.x * SCAN_BLK + t * 4;
  int s = 0;
#pragma unroll
  for (int j = 0; j < 4; j++) {
    int i = base + j;
    if (i < N_NODES) s += cnt[i];
  }
  red[t] = s;
  __syncthreads();
  for (int off = 128; off > 0; off >>= 1) {
    if (t < off) red[t] += red[t + off];
    __syncthreads();
  }
  if (t == 0) bsum[blockIdx.x] = red[0];
}

__global__ __launch_bounds__(128) void scan_bsums(const int* __restrict__ bsum,
                                                  int* __restrict__ boff) {
  __shared__ int tile[128];
  int t = threadIdx.x;
  int v = (t < N_SCAN_BLOCKS) ? bsum[t] : 0;
  tile[t] = v;
  __syncthreads();
#pragma unroll
  for (int off = 1; off < 128; off <<= 1) {
    int add = (t >= off) ? tile[t - off] : 0;
    __syncthreads();
    tile[t] += add;
    __syncthreads();
  }
  if (t < N_SCAN_BLOCKS) boff[t] = tile[t] - v;  // exclusive
}

__global__ __launch_bounds__(256) void scan_final(const int* __restrict__ cnt,
                                                  const int* __restrict__ boff,
                                                  int* __restrict__ row_ptr) {
  __shared__ int tsum[256];
  int t = threadIdx.x;
  int base = blockIdx.x * SCAN_BLK + t * 4;
  int v[4];
  int s = 0;
#pragma unroll
  for (int j = 0; j < 4; j++) {
    int i = base + j;
    v[j] = (i < N_NODES) ? cnt[i] : 0;
    s += v[j];
  }
  tsum[t] = s;
  __syncthreads();
#pragma unroll
  for (int off = 1; off < 256; off <<= 1) {
    int add = (t >= off) ? tsum[t - off] : 0;
    __syncthreads();
    tsum[t] += add;
    __syncthreads();
  }
  int excl = tsum[t] - s + boff[blockIdx.x];
#pragma unroll
  for (int j = 0; j < 4; j++) {
    int i = base + j;
    if (i < N_NODES) {
      row_ptr[i] = excl;
      excl += v[j];
    }
  }
  if (blockIdx.x == 0 && t == 0) row_ptr[N_NODES] = N_EDGES;
}

__global__ void fill_kernel(const int* __restrict__ src, const int* __restrict__ dst,
                            const int* __restrict__ row_ptr, int* __restrict__ fill,
                            int* __restrict__ col) {
  int e = blockIdx.x * blockDim.x + threadIdx.x;
  if (e < N_EDGES) {
    int d = dst[e];
    int pos = row_ptr[d] + atomicAdd(&fill[d], 1);
    col[pos] = src[e];
  }
}

// ------------------------------------------------------------ converts ------
__global__ __launch_bounds__(256) void convert_x(const float4* __restrict__ x,
                                                 ushort4* __restrict__ hb) {
  int i = blockIdx.x * blockDim.x + threadIdx.x;  // exactly N_NODES*64 threads
  float4 v = x[i];
  ushort4 o;
  o.x = f2b(v.x); o.y = f2b(v.y); o.z = f2b(v.z); o.w = f2b(v.w);
  hb[i] = o;
}

// Wt[l][n][k] bf16, k<256 -> Wl[l][k][n], k>=256 -> Wr[l][k-256][n]
__global__ __launch_bounds__(256) void convert_w(const float* __restrict__ Wl,
                                                 const float* __restrict__ Wr,
                                                 u16* __restrict__ Wt) {
  int idx = blockIdx.x * blockDim.x + threadIdx.x;  // 4*256*512 threads
  int l = idx >> 17;
  int r = idx & ((1 << 17) - 1);
  int n = r >> 9;
  int k = r & 511;
  float v = (k < 256) ? Wl[(size_t)l * 65536 + k * 256 + n]
                      : Wr[(size_t)l * 65536 + (k - 256) * 256 + n];
  Wt[idx] = f2b(v);
}

// ----------------------------------------------------------- aggregation ----
// one wave per node; two 32-lane halves process alternating edges with 16B loads;
// 4 gathers in flight per half (VGPR 28 / high occupancy); shfl_xor(32) merge.
__global__ __launch_bounds__(256) void aggregate_bf16(
    const u16* __restrict__ h, const int* __restrict__ row_ptr,
    const int* __restrict__ col, const float* __restrict__ inv_cnt,
    u16* __restrict__ aggr) {
  int node = blockIdx.x * 4 + (threadIdx.x >> 6);
  int lane = threadIdx.x & 63;
  int half = lane >> 5, l32 = lane & 31;
  int r0 = row_ptr[node], r1 = row_ptr[node + 1];
  float a[8] = {0.f, 0.f, 0.f, 0.f, 0.f, 0.f, 0.f, 0.f};
  int e = r0 + half;
  for (; e + 6 < r1; e += 8) {
    int s0 = col[e], s1 = col[e + 2], s2 = col[e + 4], s3 = col[e + 6];
    uint4 v0 = *((const uint4*)(h + (size_t)s0 * HID) + l32);
    uint4 v1 = *((const uint4*)(h + (size_t)s1 * HID) + l32);
    uint4 v2 = *((const uint4*)(h + (size_t)s2 * HID) + l32);
    uint4 v3 = *((const uint4*)(h + (size_t)s3 * HID) + l32);
    acc8(a, v0); acc8(a, v1); acc8(a, v2); acc8(a, v3);
  }
  for (; e < r1; e += 2) {
    int s0 = col[e];
    uint4 v0 = *((const uint4*)(h + (size_t)s0 * HID) + l32);
    acc8(a, v0);
  }
#pragma unroll
  for (int j = 0; j < 8; j++) a[j] += __shfl_xor(a[j], 32, 64);
  if (half == 0) {
    float inv = inv_cnt[node];
    uint4 o;
    o.x = (unsigned)f2b(a[0] * inv) | ((unsigned)f2b(a[1] * inv) << 16);
    o.y = (unsigned)f2b(a[2] * inv) | ((unsigned)f2b(a[3] * inv) << 16);
    o.z = (unsigned)f2b(a[4] * inv) | ((unsigned)f2b(a[5] * inv) << 16);
    o.w = (unsigned)f2b(a[6] * inv) | ((unsigned)f2b(a[7] * inv) << 16);
    *((uint4*)(aggr + (size_t)node * HID) + l32) = o;
  }
}

// ------------------------------------- MFMA GEMM + fused BN partials --------
// hpre[m][n] = sum_k cat(aggr,h)[m][k] * B[k][n];  B^T given as Wt[n][k].
// 128x256 tile, BK=32, 4 waves each 64x128.  Epilogue: LDS-transposed
// coalesced uint4 C-stores + per-block BN column partials -> psum[782][512].
__global__ __launch_bounds__(256, 2) void gemm_fused(
    const u16* __restrict__ hb, const u16* __restrict__ aggr,
    const u16* __restrict__ Bt, u16* __restrict__ hpre,
    float* __restrict__ psum) {
  __shared__ u16 smem[128 * 32 + 256 * 32];  // 24 KB: staging; reused as epilogue buf
  __shared__ float bns[4][8][16][2];         // 4 KB
  u16* As = smem;
  u16* Bs = smem + 128 * 32;
  u16* ep = smem;  // 32 rows x 256 cols bf16 = 16 KB (used after final K-loop sync)

  int tid = threadIdx.x;
  int wid = tid >> 6, lane = tid & 63;
  int m0 = blockIdx.x * 128;
  int q = lane >> 4, c = lane & 15;
  int wm = (wid >> 1) * 64, wn = (wid & 1) * 128;

  f32x4 zero = {0.f, 0.f, 0.f, 0.f};
  f32x4 acc[4][8];
#pragma unroll
  for (int mi = 0; mi < 4; mi++)
#pragma unroll
    for (int ni = 0; ni < 8; ni++) acc[mi][ni] = zero;

  // A staging geometry (2 issues/thread)
  int srowA0 = wid * 32 + (lane >> 2);
  int cgA0 = (lane & 3) ^ ((srowA0 >> 1) & 3);
  int srowA1 = srowA0 + 16;
  int cgA1 = (lane & 3) ^ ((srowA1 >> 1) & 3);
  // B staging geometry (4 issues/thread)
  int srowB[4], cgB[4];
#pragma unroll
  for (int j = 0; j < 4; j++) {
    srowB[j] = j * 64 + wid * 16 + (lane >> 2);
    cgB[j] = (lane & 3) ^ ((srowB[j] >> 1) & 3);
  }

  // frag-read LDS offsets (elements), loop-invariant
  int aoff[4], boff[8];
#pragma unroll
  for (int mi = 0; mi < 4; mi++) {
    int row = wm + mi * 16 + c;
    aoff[mi] = row * 32 + ((q ^ ((row >> 1) & 3)) << 3);
  }
#pragma unroll
  for (int ni = 0; ni < 8; ni++) {
    int row = wn + ni * 16 + c;
    boff[ni] = row * 32 + ((q ^ ((row >> 1) & 3)) << 3);
  }

  for (int k0 = 0; k0 < 512; k0 += 32) {
    const u16* Asrc = (k0 < 256) ? aggr : hb;
    int ksrc = k0 & 255;
    gload16(Asrc + ((size_t)(m0 + srowA0) * HID + ksrc + cgA0 * 8), &As[(wid * 32) * 32]);
    gload16(Asrc + ((size_t)(m0 + srowA1) * HID + ksrc + cgA1 * 8), &As[(wid * 32 + 16) * 32]);
#pragma unroll
    for (int j = 0; j < 4; j++)
      gload16(Bt + ((size_t)srowB[j] * 512 + k0 + cgB[j] * 8), &Bs[(j * 64 + wid * 16) * 32]);
    __syncthreads();
    bf16x8 af[4], bfr[8];
#pragma unroll
    for (int mi = 0; mi < 4; mi++) af[mi] = *(const bf16x8*)&As[aoff[mi]];
#pragma unroll
    for (int ni = 0; ni < 8; ni++) bfr[ni] = *(const bf16x8*)&Bs[boff[ni]];
#pragma unroll
    for (int mi = 0; mi < 4; mi++)
#pragma unroll
      for (int ni = 0; ni < 8; ni++)
        acc[mi][ni] = __builtin_amdgcn_mfma_f32_16x16x32_bf16(af[mi], bfr[ni],
                                                              acc[mi][ni], 0, 0, 0);
    __syncthreads();
  }

  // ---- coalesced C-store: 4 slabs of 32 rows via LDS transpose ----
  int rh = wid >> 1;  // row half (0: rows 0-63, 1: rows 64-127)
#pragma unroll
  for (int mi = 0; mi < 4; mi++) {
#pragma unroll
    for (int r = 0; r < 4; r++) {
      int r16 = q * 4 + r;
#pragma unroll
      for (int ni = 0; ni < 8; ni++)
        ep[(rh * 16 + r16) * 256 + wn + ni * 16 + c] = f2b(acc[mi][ni][r]);
    }
    __syncthreads();
    int u = tid;
#pragma unroll
    for (int j = 0; j < 4; j++, u += 256) {
      int lr = u >> 5;     // 0..31 local row
      int cu = u & 31;     // uint4 column
      int gm = m0 + (lr >> 4) * 64 + mi * 16 + (lr & 15);
      if (gm < N_NODES)
        ((uint4*)(hpre + (size_t)gm * HID))[cu] = ((const uint4*)ep)[u];
    }
    __syncthreads();
  }

  // ---- BN column partials from fp32 acc (mask pad rows) ----
#pragma unroll
  for (int ni = 0; ni < 8; ni++) {
    float s = 0.f, s2 = 0.f;
#pragma unroll
    for (int mi = 0; mi < 4; mi++) {
#pragma unroll
      for (int r = 0; r < 4; r++) {
        int gm = m0 + wm + mi * 16 + q * 4 + r;
        float v = (gm < N_NODES) ? acc[mi][ni][r] : 0.f;
        s += v;
        s2 += v * v;
      }
    }
    s += __shfl_xor(s, 16, 64);
    s += __shfl_xor(s, 32, 64);
    s2 += __shfl_xor(s2, 16, 64);
    s2 += __shfl_xor(s2, 32, 64);
    if (q == 0) {
      bns[wid][ni][c][0] = s;
      bns[wid][ni][c][1] = s2;
    }
  }
  __syncthreads();
  {
    int wnh = tid >> 7, ni = (tid >> 4) & 7, cc = tid & 15;
    float s = bns[wnh][ni][cc][0] + bns[wnh + 2][ni][cc][0];
    float s2 = bns[wnh][ni][cc][1] + bns[wnh + 2][ni][cc][1];
    int coln = wnh * 128 + ni * 16 + cc;
    psum[(size_t)blockIdx.x * 512 + coln] = s;
    psum[(size_t)blockIdx.x * 512 + 256 + coln] = s2;
  }
}

// --------------------------------- BN reduce (tree, atomic-free) ------------
#define BN_MID 16
__global__ __launch_bounds__(256) void bn_mid(const float* __restrict__ psum,
                                              float* __restrict__ tmp) {
  int b = blockIdx.x;
  int f = threadIdx.x;
  int mb0 = b * 49;
  int mb1 = min(mb0 + 49, N_MBLK);
  float s = 0.f, s2 = 0.f;
  for (int mb = mb0; mb < mb1; mb++) {
    s += psum[(size_t)mb * 512 + f];
    s2 += psum[(size_t)mb * 512 + 256 + f];
  }
  tmp[(size_t)b * 512 + f] = s;
  tmp[(size_t)b * 512 + 256 + f] = s2;
}

__global__ void bn_fin(const float* __restrict__ tmp,
                       const float* __restrict__ gamma,
                       const float* __restrict__ beta,
                       float* __restrict__ ss) {
  int f = threadIdx.x;
  float sum = 0.f, sq = 0.f;
#pragma unroll
  for (int b = 0; b < BN_MID; b++) {
    sum += tmp[(size_t)b * 512 + f];
    sq += tmp[(size_t)b * 512 + 256 + f];
  }
  const float invN = 1.0f / (float)N_NODES;
  float mu = sum * invN;
  float ex2 = sq * invN;
  float var = fmaxf(ex2 - mu * mu, 0.f);
  float sc = gamma[f] * rsqrtf(var + 1e-5f);
  ss[f] = sc;
  ss[HID + f] = beta[f] - mu * sc;
}

__global__ __launch_bounds__(256) void bn_apply_bf16(const uint4* __restrict__ hpre,
                                                     const float* __restrict__ ss,
                                                     uint4* __restrict__ hout) {
  int idx0 = blockIdx.x * blockDim.x + threadIdx.x;
  int cb = (idx0 & 31) * 8;  // column base (row = 32 uint4)
  float sc[8], sh[8];
#pragma unroll
  for (int j = 0; j < 8; j++) { sc[j] = ss[cb + j]; sh[j] = ss[HID + cb + j]; }
  const int total = N_NODES * 32;
  const int step = gridDim.x * blockDim.x;  // 524288, multiple of 32
  for (int i = idx0; i < total; i += step) {
    uint4 v = hpre[i];
    unsigned vv[4] = {v.x, v.y, v.z, v.w};
    unsigned o[4];
#pragma unroll
    for (int j = 0; j < 4; j++) {
      float lo = b2f_lo(vv[j]);
      float hi = b2f_hi(vv[j]);
      lo = fmaxf(fmaf(lo, sc[2 * j], sh[2 * j]), 0.f);
      hi = fmaxf(fmaf(hi, sc[2 * j + 1], sh[2 * j + 1]), 0.f);
      o[j] = (unsigned)f2b(lo) | ((unsigned)f2b(hi) << 16);
    }
    uint4 ov = {o[0], o[1], o[2], o[3]};
    hout[i] = ov;
  }
}

// ---------------- pool stage 1: per-(graph, chunk) BN+ReLU partial sums -----
// grid (64, 8); each block covers 1/8 of its graph's rows; atomic-free.
__global__ __launch_bounds__(256) void pool_partial(
    const u16* __restrict__ hpre, const float* __restrict__ ss,
    const int* __restrict__ batch, float* __restrict__ partial) {
  __shared__ float red[256][9];
  int g = blockIdx.x;
  int i = blockIdx.y;
  int t = threadIdx.x;
  // row range of graph g in sorted batch: [lo, hi)
  int a = 0, b = N_NODES;
  while (a < b) { int m = (a + b) >> 1; if (batch[m] < g) a = m + 1; else b = m; }
  int lo = a;
  b = N_NODES;
  while (a < b) { int m = (a + b) >> 1; if (batch[m] < g + 1) a = m + 1; else b = m; }
  int hi = a;
  int len = hi - lo;
  int clen = (len + 7) >> 3;
  int c0 = lo + i * clen;
  int c1 = min(c0 + clen, hi);

  int rs = t >> 5, cu = t & 31;
  int cb = cu * 8;
  float scv[8], shv[8];
#pragma unroll
  for (int j = 0; j < 8; j++) { scv[j] = ss[cb + j]; shv[j] = ss[HID + cb + j]; }
  float acc[8] = {0.f, 0.f, 0.f, 0.f, 0.f, 0.f, 0.f, 0.f};
  for (int r = c0 + rs; r < c1; r += 8) {
    uint4 v = *((const uint4*)(hpre + (size_t)r * HID) + cu);
    unsigned vv[4] = {v.x, v.y, v.z, v.w};
#pragma unroll
    for (int j = 0; j < 4; j++) {
      acc[2 * j]     += fmaxf(fmaf(b2f_lo(vv[j]), scv[2 * j], shv[2 * j]), 0.f);
      acc[2 * j + 1] += fmaxf(fmaf(b2f_hi(vv[j]), scv[2 * j + 1], shv[2 * j + 1]), 0.f);
    }
  }
#pragma unroll
  for (int j = 0; j < 8; j++) red[t][j] = acc[j];
  __syncthreads();
  // thread t reduces column t across the 8 row-strips
  int cc = t >> 3, j = t & 7;
  float sum = 0.f;
#pragma unroll
  for (int k = 0; k < 8; k++) sum += red[k * 32 + cc][j];
  partial[((size_t)g * 8 + i) * 256 + t] = sum;
}

// ---------------- pool stage 2 + MLP (64 blocks, reads 8 partials/graph) ----
__global__ __launch_bounds__(256) void pool_mlp_final(
    const float* __restrict__ partial, const int* __restrict__ batch,
    const float* __restrict__ W1, const float* __restrict__ b1,
    const float* __restrict__ W2, const float* __restrict__ b2,
    float* __restrict__ out) {
  __shared__ float gs[HID];
  __shared__ float ts[HID];
  __shared__ float rn[PROJ];
  int g = blockIdx.x;
  int t = threadIdx.x;
  // graph length via binary search
  int a = 0, b = N_NODES;
  while (a < b) { int m = (a + b) >> 1; if (batch[m] < g) a = m + 1; else b = m; }
  int lo = a;
  b = N_NODES;
  while (a < b) { int m = (a + b) >> 1; if (batch[m] < g + 1) a = m + 1; else b = m; }
  int len = a - lo;

  float sum = 0.f;
#pragma unroll
  for (int i = 0; i < 8; i++) sum += partial[((size_t)g * 8 + i) * 256 + t];
  float inv = 1.0f / fmaxf((float)len, 1.0f);
  gs[t] = sum * inv;
  __syncthreads();

  float s = b1[t];
  for (int k = 0; k < HID; k++) s = fmaf(gs[k], W1[(size_t)k * HID + t], s);
  ts[t] = fmaxf(s, 0.f);
  __syncthreads();
  float z = 0.f;
  if (t < PROJ) {
    z = b2[t];
    for (int k = 0; k < HID; k++) z = fmaf(ts[k], W2[(size_t)k * PROJ + t], z);
    rn[t] = z * z;
  }
  __syncthreads();
  for (int off = PROJ / 2; off > 0; off >>= 1) {
    if (t < off) rn[t] += rn[t + off];
    __syncthreads();
  }
  float norm = fmaxf(sqrtf(rn[0]), 1e-12f);
  if (t < PROJ) out[(size_t)g * PROJ + t] = z / norm;
}

// --------------------------------------------------------------- launch -----
extern "C" void kernel_launch(void* const* d_in, const int* in_sizes, int n_in,
                              void* d_out, int out_size, void* d_ws, size_t ws_size,
                              hipStream_t stream) {
  const float* x = (const float*)d_in[0];
  const int* ei = (const int*)d_in[1];
  const int* src = ei;
  const int* dst = ei + N_EDGES;
  const int* batch = (const int*)d_in[2];
  const float* Wl = (const float*)d_in[3];
  // d_in[4] = bl: per-column bias is exactly cancelled by BatchNorm -> unused
  const float* Wr = (const float*)d_in[5];
  const float* gamma = (const float*)d_in[6];
  const float* beta = (const float*)d_in[7];
  const float* W1 = (const float*)d_in[8];
  const float* b1 = (const float*)d_in[9];
  const float* W2 = (const float*)d_in[10];
  const float* b2 = (const float*)d_in[11];
  float* out = (float*)d_out;

  char* p = (char*)d_ws;
  const size_t HB = (size_t)M_PAD * HID * sizeof(u16);  // 51.25 MB
  u16* hb0 = (u16*)p;    p += HB;
  u16* hb1 = (u16*)p;    p += HB;
  u16* aggr = (u16*)p;   p += HB;
  u16* hpre = (u16*)p;   p += HB;
  u16* Wt = (u16*)p;     p += (size_t)NLAYERS * 512 * HID * sizeof(u16);  // 1 MB
  int* col = (int*)p;    p += (size_t)N_EDGES * sizeof(int);              // 6.4 MB
  int* row_ptr = (int*)p; p += 400016;
  float* inv_cnt = (float*)p; p += (size_t)N_NODES * sizeof(float);
  float* psum = (float*)p;    p += (size_t)N_MBLK * 512 * sizeof(float);  // 1.6 MB
  float* tmp = (float*)p;     p += (size_t)BN_MID * 512 * sizeof(float);
  float* ss = (float*)p;      p += 512 * sizeof(float);
  float* partial = (float*)p; p += (size_t)N_GRAPHS * 8 * 256 * sizeof(float);
  int* bsum = (int*)p;        p += 128 * sizeof(int);
  int* boff = (int*)p;        p += 128 * sizeof(int);

  // transient CSR-build arrays overlaid into hpre (first written in layer-0 gemm)
  int* counts = (int*)hpre;
  int* fill = counts + N_NODES;

  // ---- build CSR (once; edge_index is layer-invariant) ----
  hipMemsetAsync(counts, 0, 2 * (size_t)N_NODES * sizeof(int), stream);
  count_kernel<<<(N_EDGES + 255) / 256, 256, 0, stream>>>(dst, counts);
  inv_kernel<<<(N_NODES + 255) / 256, 256, 0, stream>>>(counts, inv_cnt);
  scan_partial<<<N_SCAN_BLOCKS, 256, 0, stream>>>(counts, bsum);
  scan_bsums<<<1, 128, 0, stream>>>(bsum, boff);
  scan_final<<<N_SCAN_BLOCKS, 256, 0, stream>>>(counts, boff, row_ptr);
  fill_kernel<<<(N_EDGES + 255) / 256, 256, 0, stream>>>(src, dst, row_ptr, fill, col);

  // ---- one-time converts ----
  convert_x<<<N_NODES / 4, 256, 0, stream>>>((const float4*)x, (ushort4*)hb0);
  convert_w<<<(NLAYERS * 512 * HID) / 256, 256, 0, stream>>>(Wl, Wr, Wt);

  u16* hcur = hb0;
  u16* hnext = hb1;
  for (int l = 0; l < NLAYERS; l++) {
    aggregate_bf16<<<N_NODES / 4, 256, 0, stream>>>(hcur, row_ptr, col, inv_cnt, aggr);
    gemm_fused<<<N_MBLK, 256, 0, stream>>>(hcur, aggr, Wt + (size_t)l * 512 * HID,
                                           hpre, psum);
    bn_mid<<<BN_MID, 256, 0, stream>>>(psum, tmp);
    bn_fin<<<1, 256, 0, stream>>>(tmp, gamma + (size_t)l * HID,
                                  beta + (size_t)l * HID, ss);
    if (l < NLAYERS - 1) {
      bn_apply_bf16<<<2048, 256, 0, stream>>>((const uint4*)hpre, ss, (uint4*)hnext);
      u16* t = hcur; hcur = hnext; hnext = t;
    }
  }

  // layer-3 BN+ReLU fused into two-stage pooling (reads hpre + ss)
  pool_partial<<<dim3(N_GRAPHS, 8), 256, 0, stream>>>(hpre, ss, batch, partial);
  pool_mlp_final<<<N_GRAPHS, 256, 0, stream>>>(partial, batch, W1, b1, W2, b2, out);
}